// Round 14
// baseline (344.585 us; speedup 1.0000x reference)
//
#include <hip/hip_runtime.h>
#include <hip/hip_bf16.h>
#include <cstdint>
#include <cstddef>

// ---------------------------------------------------------------------------
// CausalSelfAttention fused block, MI355X/gfx950.  Round 14:
//  - attn: SWAPPED QK^T (S^T = mfma(K,Q)) -> softmax row-reductions are
//    lane-local (0 shuffles common path), P stored as 4x b64 (was 16 scalar),
//    all LDS XOR-swizzled unpadded: 40960B -> 4 blocks/CU.
//  - KV-split + combine dropped (R13 null result).
//  - GEMMs/epilogue/vtrans unchanged (R11/R12 proven).
// B=2 T=2048 D=2048 NH=16 NKV=4 HD=128 ROPE=64.
// ---------------------------------------------------------------------------

typedef _Float16 f16_t;
typedef f16_t f16x4 __attribute__((ext_vector_type(4)));
typedef f16_t f16x8 __attribute__((ext_vector_type(8)));
typedef float f32x4 __attribute__((ext_vector_type(4)));

#define MFMA16F(a, b, c) __builtin_amdgcn_mfma_f32_16x16x32_f16((a), (b), (c), 0, 0, 0)
#define SBAR()   __builtin_amdgcn_s_barrier()
#define SCHED0() __builtin_amdgcn_sched_barrier(0)
#define LGKM0()  asm volatile("s_waitcnt lgkmcnt(0)" ::: "memory")

__device__ __forceinline__ void gload16(const f16_t* g, f16_t* l) {
  auto lds_ptr = reinterpret_cast<__attribute__((address_space(3))) unsigned int*>(
      reinterpret_cast<uintptr_t>(l));
  auto g_ptr = reinterpret_cast<const __attribute__((address_space(1))) unsigned int*>(
      reinterpret_cast<uintptr_t>(g));
  __builtin_amdgcn_global_load_lds(g_ptr, lds_ptr, 16, 0, 0);
}

// ---------------------------------------------------------------------------
// fp32 -> fp16 cast, vectorized
// ---------------------------------------------------------------------------
__global__ void k_cast_f16(const float* __restrict__ in, f16_t* __restrict__ o, long n) {
  long i = ((long)blockIdx.x * blockDim.x + threadIdx.x) * 4;
  const long step = (long)gridDim.x * blockDim.x * 4;
  for (; i < n; i += step) {
    const float4 v = *reinterpret_cast<const float4*>(in + i);
    f16_t r[4] = {(f16_t)v.x, (f16_t)v.y, (f16_t)v.z, (f16_t)v.w};
    *reinterpret_cast<uint64_t*>(o + i) = *reinterpret_cast<const uint64_t*>(r);
  }
}

// ---------------------------------------------------------------------------
// merged W cast: rows 0-2047 Wq, 2048-2559 Wk, 2560-3071 Wv -> wf [3072][2048]
// ---------------------------------------------------------------------------
__global__ void k_cast_wqkv(const float* __restrict__ Wq, const float* __restrict__ Wk,
                            const float* __restrict__ Wv, f16_t* __restrict__ wf) {
  long i = ((long)blockIdx.x * blockDim.x + threadIdx.x) * 4;
  const long step = (long)gridDim.x * blockDim.x * 4;
  for (; i < (long)3072 * 2048; i += step) {
    const long row = i >> 11, col = i & 2047;
    const float* src = (row < 2048) ? (Wq + (size_t)row * 2048)
                     : (row < 2560) ? (Wk + (size_t)(row - 2048) * 2048)
                                    : (Wv + (size_t)(row - 2560) * 2048);
    const float4 v = *reinterpret_cast<const float4*>(src + col);
    f16_t r[4] = {(f16_t)v.x, (f16_t)v.y, (f16_t)v.z, (f16_t)v.w};
    *reinterpret_cast<uint64_t*>(wf + row * 2048 + col) = *reinterpret_cast<const uint64_t*>(r);
  }
}

// ---------------------------------------------------------------------------
// RoPE cos/sin table: [T=2048][32]
// ---------------------------------------------------------------------------
__global__ void k_rope_tab(float* __restrict__ ctab, float* __restrict__ stab) {
  const int idx = blockIdx.x * blockDim.x + threadIdx.x;
  if (idx >= 2048 * 32) return;
  const int t = idx >> 5, i = idx & 31;
  const float freq = exp2f(-(float)i * 0.2076205059304601f);  // 10000^(-i/64)
  const float f = (float)t * freq;
  ctab[idx] = cosf(f);
  stab[idx] = sinf(f);
}

// ---------------------------------------------------------------------------
// V transpose: vn [bk][2048 t][128 d] -> vt [bk][128 d][2048 t].
// ---------------------------------------------------------------------------
__global__ __launch_bounds__(256) void k_vtrans(
    const f16_t* __restrict__ vn, f16_t* __restrict__ vt)
{
  __shared__ __align__(16) f16_t lsT[64 * 136];
  const int t0 = blockIdx.x * 64;
  const int bk = blockIdx.y;
  const f16_t* src = vn + ((size_t)bk * 2048 + t0) * 128;
  f16_t* dst = vt + (size_t)bk * 128 * 2048;
  const int tid = threadIdx.x;
#pragma unroll
  for (int it = 0; it < 4; ++it) {
    const int cch = tid + it * 256;
    const int r = cch >> 4, c = cch & 15;
    *reinterpret_cast<f16x8*>(&lsT[r * 136 + c * 8]) =
        *reinterpret_cast<const f16x8*>(src + (size_t)r * 128 + c * 8);
  }
  __syncthreads();
#pragma unroll
  for (int it = 0; it < 4; ++it) {
    const int u = tid + it * 256;
    const int d = u >> 3, c8 = u & 7;
    f16_t vals[8];
#pragma unroll
    for (int j = 0; j < 8; ++j) vals[j] = lsT[(c8 * 8 + j) * 136 + d];
    *reinterpret_cast<f16x8*>(dst + (size_t)d * 2048 + t0 + c8 * 8) =
        *reinterpret_cast<const f16x8*>(vals);
  }
}

// ---------------------------------------------------------------------------
// 256 x (64*NBU) NT GEMM, fp16 in, OutT out (R10/R11 proven).
// 1024 threads = 16 waves (4M x 4N); BK=64; 2-phase counted-vmcnt.
// ---------------------------------------------------------------------------
template <int NBU, typename OutT>
__global__ __launch_bounds__(1024, 1) void k_gemmQ(
    const f16_t* __restrict__ A, const f16_t* __restrict__ Bm,
    OutT* __restrict__ C, int M, int N, int K, int lda, int ldb)
{
  __shared__ __align__(16) f16_t lds[2][(4 + NBU) * 4096];
  const int tid = threadIdx.x;
  const int l = tid & 63, w = tid >> 6;       // w 0..15
  const int lrow = l & 15, lk = l >> 4;
  const int wm = w >> 2, wn = w & 3;          // 4 x 4 wave grid

  const int nwg = gridDim.x * gridDim.y;
  int lin = blockIdx.y * gridDim.x + blockIdx.x;
  lin = (lin & 7) * (nwg >> 3) + (lin >> 3);
  const int m0 = (lin / gridDim.x) * 256, n0 = (lin % gridDim.x) * (64 * NBU);

  const bool stager = (tid < 512);
  const int srow = tid >> 3;
  const int scol = ((tid & 7) ^ (srow & 7)) << 3;
  const f16_t* gP[4 + NBU];
#pragma unroll
  for (int u = 0; u < 4; ++u) gP[u] = A + (size_t)(m0 + u * 64 + srow) * lda + scol;
#pragma unroll
  for (int u = 0; u < NBU; ++u) gP[4 + u] = Bm + (size_t)(n0 + u * 64 + srow) * ldb + scol;

  auto stageAll = [&](int buf, int k0) {
#pragma unroll
    for (int u = 0; u < 4 + NBU; ++u)
      gload16(gP[u] + k0, &lds[buf][u * 4096 + tid * 8]);
  };
  auto rdA = [&](int buf, int mf, int ks) -> f16x8 {
    const int row = wm * 64 + mf * 16 + lrow;             // 0..255
    const int slot = ((ks << 2) | lk) ^ (row & 7);
    return *reinterpret_cast<const f16x8*>(&lds[buf][row * 64 + slot * 8]);
  };
  auto rdB = [&](int buf, int nf, int ks) -> f16x8 {
    const int row = wn * (16 * NBU) + nf * 16 + lrow;     // 0..64*NBU-1
    const int slot = ((ks << 2) | lk) ^ (row & 7);
    return *reinterpret_cast<const f16x8*>(&lds[buf][16384 + row * 64 + slot * 8]);
  };

  f32x4 acc[4][NBU] = {};
  const int nkt = K >> 6;

  if (stager) {
    stageAll(0, 0);
    stageAll(1, nkt > 1 ? 64 : 0);
  }
  if constexpr (NBU == 3) { asm volatile("s_waitcnt vmcnt(7)" ::: "memory"); }
  else                    { asm volatile("s_waitcnt vmcnt(6)" ::: "memory"); }
  SCHED0();
  SBAR(); SCHED0();

  f16x8 aA[4][2], bB[NBU][2];
  for (int kt = 0; kt < nkt; ++kt) {
    const int b = kt & 1;
    const int kn2 = (kt + 2 < nkt ? kt + 2 : nkt - 1) << 6;

    // phase 1: read all frags of tile t, MFMA mf 0..1
#pragma unroll
    for (int mf = 0; mf < 4; ++mf) { aA[mf][0] = rdA(b, mf, 0); aA[mf][1] = rdA(b, mf, 1); }
#pragma unroll
    for (int nf = 0; nf < NBU; ++nf) { bB[nf][0] = rdB(b, nf, 0); bB[nf][1] = rdB(b, nf, 1); }
    __builtin_amdgcn_s_setprio(1);
#pragma unroll
    for (int mf = 0; mf < 2; ++mf)
#pragma unroll
      for (int nf = 0; nf < NBU; ++nf)
#pragma unroll
        for (int ks = 0; ks < 2; ++ks)
          acc[mf][nf] = MFMA16F(aA[mf][ks], bB[nf][ks], acc[mf][nf]);
    __builtin_amdgcn_s_setprio(0);
    LGKM0(); SCHED0();
    SBAR(); SCHED0();

    // phase 2: stage tile t+2 over dead buf b; wait tile t+1; MFMA mf 2..3
    if (stager) stageAll(b, kn2);
    if constexpr (NBU == 3) { asm volatile("s_waitcnt vmcnt(7)" ::: "memory"); }
    else                    { asm volatile("s_waitcnt vmcnt(6)" ::: "memory"); }
    SCHED0();
    __builtin_amdgcn_s_setprio(1);
#pragma unroll
    for (int mf = 2; mf < 4; ++mf)
#pragma unroll
      for (int nf = 0; nf < NBU; ++nf)
#pragma unroll
        for (int ks = 0; ks < 2; ++ks)
          acc[mf][nf] = MFMA16F(aA[mf][ks], bB[nf][ks], acc[mf][nf]);
    __builtin_amdgcn_s_setprio(0);
    SBAR(); SCHED0();
  }

  // C-write
#pragma unroll
  for (int mf = 0; mf < 4; ++mf) {
    const int row = m0 + wm * 64 + mf * 16 + lk * 4;
#pragma unroll
    for (int nf = 0; nf < NBU; ++nf) {
      const int col = n0 + wn * (16 * NBU) + nf * 16 + lrow;
#pragma unroll
      for (int rg = 0; rg < 4; ++rg)
        C[(size_t)(row + rg) * N + col] = (OutT)acc[mf][nf][rg];
    }
  }
  (void)M;
}

// ---------------------------------------------------------------------------
// QKV epilogue (unchanged from R11).
// ---------------------------------------------------------------------------
__global__ __launch_bounds__(256) void k_qkv_epi(
    const f16_t* __restrict__ qkv, const float* __restrict__ ve,
    const float* __restrict__ qgain,
    const float* __restrict__ ctab, const float* __restrict__ stab,
    f16_t* __restrict__ qn, f16_t* __restrict__ kn, f16_t* __restrict__ vn)
{
  const int blk = blockIdx.x;           // b*2048 + t
  const int b = blk >> 11, t = blk & 2047;
  const int w = threadIdx.x >> 6, l = threadIdx.x & 63;
  const int i32 = l & 31;
  const float c = ctab[t * 32 + i32], s = stab[t * 32 + i32];
  const float EPS = 1.1920929e-07f;
  constexpr float SCALE_L2E = 0.088388347648318447f * 1.4426950408889634f;

#pragma unroll
  for (int it = 0; it < 4; ++it) {
    const int h = w + it * 4;
    const f16_t* row = qkv + (size_t)blk * 3072 + h * 128;
    float x0 = (float)row[l], x1 = (float)row[l + 64];
    float ss = x0 * x0 + x1 * x1;
#pragma unroll
    for (int off = 32; off; off >>= 1) ss += __shfl_xor(ss, off);
    const float rn = rsqrtf(ss * (1.0f / 128.0f) + EPS);
    x0 *= rn; x1 *= rn;
    const float p = __shfl_xor(x0, 32);
    float xr = (l < 32) ? (x0 * c - p * s) : (p * s + x0 * c);
    const float g = qgain[h] * SCALE_L2E;
    xr *= g; x1 *= g;
    f16_t* orow = qn + (((size_t)(b * 16 + h)) * 2048 + t) * 128;
    orow[l] = (f16_t)xr;
    orow[l + 64] = (f16_t)x1;
  }
  {
    const f16_t* row = qkv + (size_t)blk * 3072 + 2048 + w * 128;
    float x0 = (float)row[l], x1 = (float)row[l + 64];
    float ss = x0 * x0 + x1 * x1;
#pragma unroll
    for (int off = 32; off; off >>= 1) ss += __shfl_xor(ss, off);
    const float rn = rsqrtf(ss * (1.0f / 128.0f) + EPS);
    x0 *= rn; x1 *= rn;
    const float p = __shfl_xor(x0, 32);
    const float xr = (l < 32) ? (x0 * c - p * s) : (p * s + x0 * c);
    f16_t* orow = kn + (((size_t)(b * 4 + w)) * 2048 + t) * 128;
    orow[l] = (f16_t)xr;
    orow[l + 64] = (f16_t)x1;
  }
  {
    const f16_t* row = qkv + (size_t)blk * 3072 + 2560 + w * 128;
    const float* verow = ve + (size_t)blk * 512 + w * 128;
    f16_t* orow = vn + (((size_t)(b * 4 + w)) * 2048 + t) * 128;
    orow[l] = (f16_t)((float)row[l] + verow[l]);
    orow[l + 64] = (f16_t)((float)row[l + 64] + verow[l + 64]);
  }
}

// ---------------------------------------------------------------------------
// Causal GQA flash attention, fp16, swapped QK^T.  QBLK=64 (4 waves x 16
// q-rows), KVBLK=64, longest-qt-first.  S^T = mfma(K,Q): lane holds
// S[q=lrow][kv=cf*16+lk*4+rg] -> lane-local softmax.  LDS (all XOR-swizzled,
// 40960B -> 4 blocks/CU): lsK [64][128], lsV^T [128][64], lsP [4][16][64].
// ---------------------------------------------------------------------------
__global__ __launch_bounds__(256, 4) void k_attn(
    const f16_t* __restrict__ qn, const f16_t* __restrict__ kn,
    const f16_t* __restrict__ vt, f16_t* __restrict__ y)
{
  __shared__ __align__(16) f16_t lsK[64 * 128];      // 16384 B
  __shared__ __align__(16) f16_t lsV[128 * 64];      // 16384 B
  __shared__ __align__(16) f16_t lsPb[4][16 * 64];   //  8192 B
  const int qt = 31 - (int)blockIdx.y;  // longest first
  const int bh = blockIdx.x;            // 0..31
  const int b = bh >> 4, h = bh & 15, kvh = h >> 2;
  const int tid = threadIdx.x, w = tid >> 6, l = tid & 63;
  const int lrow = l & 15, lk = l >> 4;
  const int qbase = qt * 64 + w * 16;
  constexpr float NEG = -1e30f;
  f16_t* lsP = lsPb[w];

  // Q fragments (same layout for A- and B-operand: row/col = lane&15,
  // k = lk*8+j)
  const f16_t* qp = qn + ((size_t)(b * 16 + h) * 2048) * 128;
  f16x8 aQ[4];
#pragma unroll
  for (int kf = 0; kf < 4; ++kf)
    aQ[kf] = *reinterpret_cast<const f16x8*>(
        qp + (size_t)(qbase + lrow) * 128 + kf * 32 + lk * 8);

  const f16_t* kp = kn + ((size_t)(b * 4 + kvh) * 2048) * 128;
  const f16_t* vtp = vt + (size_t)(b * 4 + kvh) * 128 * 2048;

  f32x4 o[8] = {};
  float mst = NEG;   // running max for THIS LANE's q-row (q = lrow); row-consistent
  float lst = 0.f;   // per-lane partial sum for q = lrow (reduced at end)

  f16x8 kreg[4], vreg[4];
  auto loadKV = [&](int t0) {
#pragma unroll
    for (int it = 0; it < 4; ++it) {
      const int cch = tid + it * 256;
      kreg[it] = *reinterpret_cast<const f16x8*>(
          kp + (size_t)(t0 + (cch >> 4)) * 128 + (cch & 15) * 8);
      vreg[it] = *reinterpret_cast<const f16x8*>(
          vtp + (size_t)(cch >> 3) * 2048 + t0 + (cch & 7) * 8);
    }
  };
  loadKV(0);

  const int ntiles = qt + 1;
  for (int tt = 0; tt < ntiles; ++tt) {
    __syncthreads();  // prior tile's K/V LDS reads done before restage
    // stage K [64][128] slot^=(r&7); V^T [128][64] slot^=((d>>3)&7); all b128
#pragma unroll
    for (int it = 0; it < 4; ++it) {
      const int cch = tid + it * 256;
      const int r = cch >> 4, dg = cch & 15;
      *reinterpret_cast<f16x8*>(&lsK[r * 128 + ((dg ^ (r & 7)) << 3)]) = kreg[it];
      const int d = cch >> 3, c8 = cch & 7;
      *reinterpret_cast<f16x8*>(&lsV[d * 64 + ((c8 ^ ((d >> 3) & 7)) << 3)]) = vreg[it];
    }
    if (tt + 1 < ntiles) loadKV((tt + 1) * 64);
    __syncthreads();  // staged data visible

    // S^T = K Q^T: sacc[cf][rg] = S[q=lrow][kv = cf*16 + lk*4 + rg]
    f32x4 sacc[4] = {};
#pragma unroll
    for (int cf = 0; cf < 4; ++cf) {
      const int krow = cf * 16 + lrow;
#pragma unroll
      for (int kf = 0; kf < 4; ++kf) {
        const f16x8 aK = *reinterpret_cast<const f16x8*>(
            &lsK[krow * 128 + ((((kf << 2) | lk) ^ (krow & 7)) << 3)]);
        sacc[cf] = MFMA16F(aK, aQ[kf], sacc[cf]);
      }
    }

    // mask (diagonal tile only): kv_in_tile > q_in_block
    if (tt == qt) {
      const int qin = w * 16 + lrow;
#pragma unroll
      for (int cf = 0; cf < 4; ++cf)
#pragma unroll
        for (int rg = 0; rg < 4; ++rg)
          if (cf * 16 + lk * 4 + rg > qin) sacc[cf][rg] = NEG;
    }

    // lane-local max of this tile's 16 values
    float mx = NEG;
#pragma unroll
    for (int cf = 0; cf < 4; ++cf)
      mx = fmaxf(mx, fmaxf(fmaxf(sacc[cf][0], sacc[cf][1]),
                           fmaxf(sacc[cf][2], sacc[cf][3])));
    if (__any(mx > mst + 8.f)) {
      // row-consistent new max over the 4 lk-lanes holding this q-row
      float rmx = mx;
      rmx = fmaxf(rmx, __shfl_xor(rmx, 16));
      rmx = fmaxf(rmx, __shfl_xor(rmx, 32));
      const float mnew = fmaxf(mst, rmx);
      const float alpha = exp2f(mst - mnew);
      mst = mnew;
      lst *= alpha;
      // o rows are q = lk*4+rg; fetch that row's alpha from lane (lk*4+rg)
#pragma unroll
      for (int rg = 0; rg < 4; ++rg) {
        const float arow = __shfl(alpha, lk * 4 + rg);
#pragma unroll
        for (int df = 0; df < 8; ++df) o[df][rg] *= arow;
      }
    }
    // P = exp2(S - mst), lane-local partial sum
#pragma unroll
    for (int cf = 0; cf < 4; ++cf) {
#pragma unroll
      for (int rg = 0; rg < 4; ++rg) {
        const float p = exp2f(sacc[cf][rg] - mst);
        sacc[cf][rg] = p;
        lst += p;
      }
    }

    // P -> LDS [q=16][kv=64], b64 per cf (kv = cf*16+lk*4 .. +3), XOR slot8
#pragma unroll
    for (int cf = 0; cf < 4; ++cf) {
      f16x4 pk;
#pragma unroll
      for (int rg = 0; rg < 4; ++rg) pk[rg] = (f16_t)sacc[cf][rg];
      const int slot8 = cf * 2 + (lk >> 1);
      *reinterpret_cast<f16x4*>(
          &lsP[lrow * 64 + ((slot8 ^ (lrow & 7)) << 3) + (lk & 1) * 4]) = pk;
    }
    // PV: aP = P[q=lrow][kv=k2*32+lk*8+j]; bV = V[kv][d=df*16+lrow]
#pragma unroll
    for (int k2 = 0; k2 < 2; ++k2) {
      const f16x8 aP = *reinterpret_cast<const f16x8*>(
          &lsP[lrow * 64 + ((((k2 << 2) | lk) ^ (lrow & 7)) << 3)]);
#pragma unroll
      for (int df = 0; df < 8; ++df) {
        const int row = df * 16 + lrow;
        const f16x8 bV = *reinterpret_cast<const f16x8*>(
            &lsV[row * 64 + ((((k2 << 2) | lk) ^ ((row >> 3) & 7)) << 3)]);
        o[df] = MFMA16F(aP, bV, o[df]);
      }
    }
  }

  // reduce lst over the 4 lk-lanes of each q-row (all 4 copies equal after)
  lst += __shfl_xor(lst, 16);
  lst += __shfl_xor(lst, 32);

  // normalize + write y: o[df][rg] is q = lk*4+rg, d = df*16+lrow
#pragma unroll
  for (int rg = 0; rg < 4; ++rg) {
    const float lrow_sum = __shfl(lst, lk * 4 + rg);
    const float inv = 1.0f / lrow_sum;
    const int qi = qbase + lk * 4 + rg;
    const size_t rowoff = ((size_t)(b * 2048 + qi)) * 2048 + h * 128;
#pragma unroll
    for (int df = 0; df < 8; ++df)
      y[rowoff + df * 16 + lrow] = (f16_t)(o[df][rg] * inv);
  }
}

// ---------------------------------------------------------------------------
extern "C" void kernel_launch(void* const* d_in, const int* in_sizes, int n_in,
                              void* d_out, int out_size, void* d_ws, size_t ws_size,
                              hipStream_t stream) {
  const float* x  = (const float*)d_in[0];
  const float* ve = (const float*)d_in[1];
  const float* Wq = (const float*)d_in[2];
  const float* Wk = (const float*)d_in[3];
  const float* Wv = (const float*)d_in[4];
  const float* Wp = (const float*)d_in[5];
  const float* qg = (const float*)d_in[6];
  float* out = (float*)d_out;

  char* ws = (char*)d_ws;
  size_t off = 0;
  auto alloc = [&](size_t bytes) -> char* {
    char* p = ws + off;
    off += (bytes + 255) & ~(size_t)255;
    return p;
  };

  f16_t* xf    = (f16_t*)alloc((size_t)4096 * 2048 * 2);   // later qn
  f16_t* wqkvf = (f16_t*)alloc((size_t)3072 * 2048 * 2);   // rows Wq|Wk|Wv
  f16_t* wpf   = (f16_t*)alloc((size_t)2048 * 2048 * 2);
  f16_t* qkvf  = (f16_t*)alloc((size_t)4096 * 3072 * 2);   // GEMM out; later yb
  f16_t* kn    = (f16_t*)alloc((size_t)2 * 4 * 2048 * 128 * 2);
  f16_t* vn    = (f16_t*)alloc((size_t)2 * 4 * 2048 * 128 * 2);
  f16_t* vt    = (f16_t*)alloc((size_t)2 * 4 * 128 * 2048 * 2);
  float* ctab  = (float*)alloc((size_t)2048 * 32 * 4);
  float* stab  = (float*)alloc((size_t)2048 * 32 * 4);
  f16_t* qn    = xf;      // xf dead after QKV GEMM
  f16_t* yb    = qkvf;    // qkvf dead after epilogue
  (void)ws_size; (void)in_sizes; (void)n_in; (void)out_size;

  k_cast_f16<<<1024, 256, 0, stream>>>(x, xf, (long)4096 * 2048);
  k_cast_wqkv<<<1536, 256, 0, stream>>>(Wq, Wk, Wv, wqkvf);
  k_cast_f16<<<1024, 256, 0, stream>>>(Wp, wpf, (long)2048 * 2048);
  k_rope_tab<<<256, 256, 0, stream>>>(ctab, stab);

  // qkvf = x·[Wq|Wk|Wv]^T  (M=4096 N=3072 K=2048; 256x192 tiles, grid 16x16)
  k_gemmQ<3, f16_t><<<dim3(16, 16), 1024, 0, stream>>>(
      xf, wqkvf, qkvf, 4096, 3072, 2048, 2048, 2048);

  k_qkv_epi<<<4096, 256, 0, stream>>>(qkvf, ve, qg, ctab, stab, qn, kn, vn);

  k_vtrans<<<dim3(32, 8), 256, 0, stream>>>(vn, vt);

  k_attn<<<dim3(32, 32), 256, 0, stream>>>(qn, kn, vt, yb);

  // out = y · Wp^T  (M=4096 N=2048 K=2048; 256x128 tiles, grid 16x16)
  k_gemmQ<2, float><<<dim3(16, 16), 1024, 0, stream>>>(
      yb, wpf, out, 4096, 2048, 2048, 2048, 2048);
}

// Round 15
// 206.997 us; speedup vs baseline: 1.6647x; 1.6647x over previous
//
#include <hip/hip_runtime.h>
#include <hip/hip_bf16.h>
#include <cstdint>
#include <cstddef>

// ---------------------------------------------------------------------------
// CausalSelfAttention fused block, MI355X/gfx950.  Round 15:
//  - R14's swapped-QK^T attn with launch_bounds(256,3): R14's (256,4) capped
//    VGPR at 64 -> spills (WRITE_SIZE 110MB scratch).  One-line fix.
//  - GEMMs/epilogue/vtrans unchanged.
// B=2 T=2048 D=2048 NH=16 NKV=4 HD=128 ROPE=64.
// ---------------------------------------------------------------------------

typedef _Float16 f16_t;
typedef f16_t f16x4 __attribute__((ext_vector_type(4)));
typedef f16_t f16x8 __attribute__((ext_vector_type(8)));
typedef float f32x4 __attribute__((ext_vector_type(4)));

#define MFMA16F(a, b, c) __builtin_amdgcn_mfma_f32_16x16x32_f16((a), (b), (c), 0, 0, 0)
#define SBAR()   __builtin_amdgcn_s_barrier()
#define SCHED0() __builtin_amdgcn_sched_barrier(0)
#define LGKM0()  asm volatile("s_waitcnt lgkmcnt(0)" ::: "memory")

__device__ __forceinline__ void gload16(const f16_t* g, f16_t* l) {
  auto lds_ptr = reinterpret_cast<__attribute__((address_space(3))) unsigned int*>(
      reinterpret_cast<uintptr_t>(l));
  auto g_ptr = reinterpret_cast<const __attribute__((address_space(1))) unsigned int*>(
      reinterpret_cast<uintptr_t>(g));
  __builtin_amdgcn_global_load_lds(g_ptr, lds_ptr, 16, 0, 0);
}

// ---------------------------------------------------------------------------
// fp32 -> fp16 cast, vectorized
// ---------------------------------------------------------------------------
__global__ void k_cast_f16(const float* __restrict__ in, f16_t* __restrict__ o, long n) {
  long i = ((long)blockIdx.x * blockDim.x + threadIdx.x) * 4;
  const long step = (long)gridDim.x * blockDim.x * 4;
  for (; i < n; i += step) {
    const float4 v = *reinterpret_cast<const float4*>(in + i);
    f16_t r[4] = {(f16_t)v.x, (f16_t)v.y, (f16_t)v.z, (f16_t)v.w};
    *reinterpret_cast<uint64_t*>(o + i) = *reinterpret_cast<const uint64_t*>(r);
  }
}

// ---------------------------------------------------------------------------
// merged W cast: rows 0-2047 Wq, 2048-2559 Wk, 2560-3071 Wv -> wf [3072][2048]
// ---------------------------------------------------------------------------
__global__ void k_cast_wqkv(const float* __restrict__ Wq, const float* __restrict__ Wk,
                            const float* __restrict__ Wv, f16_t* __restrict__ wf) {
  long i = ((long)blockIdx.x * blockDim.x + threadIdx.x) * 4;
  const long step = (long)gridDim.x * blockDim.x * 4;
  for (; i < (long)3072 * 2048; i += step) {
    const long row = i >> 11, col = i & 2047;
    const float* src = (row < 2048) ? (Wq + (size_t)row * 2048)
                     : (row < 2560) ? (Wk + (size_t)(row - 2048) * 2048)
                                    : (Wv + (size_t)(row - 2560) * 2048);
    const float4 v = *reinterpret_cast<const float4*>(src + col);
    f16_t r[4] = {(f16_t)v.x, (f16_t)v.y, (f16_t)v.z, (f16_t)v.w};
    *reinterpret_cast<uint64_t*>(wf + row * 2048 + col) = *reinterpret_cast<const uint64_t*>(r);
  }
}

// ---------------------------------------------------------------------------
// RoPE cos/sin table: [T=2048][32]
// ---------------------------------------------------------------------------
__global__ void k_rope_tab(float* __restrict__ ctab, float* __restrict__ stab) {
  const int idx = blockIdx.x * blockDim.x + threadIdx.x;
  if (idx >= 2048 * 32) return;
  const int t = idx >> 5, i = idx & 31;
  const float freq = exp2f(-(float)i * 0.2076205059304601f);  // 10000^(-i/64)
  const float f = (float)t * freq;
  ctab[idx] = cosf(f);
  stab[idx] = sinf(f);
}

// ---------------------------------------------------------------------------
// V transpose: vn [bk][2048 t][128 d] -> vt [bk][128 d][2048 t].
// ---------------------------------------------------------------------------
__global__ __launch_bounds__(256) void k_vtrans(
    const f16_t* __restrict__ vn, f16_t* __restrict__ vt)
{
  __shared__ __align__(16) f16_t lsT[64 * 136];
  const int t0 = blockIdx.x * 64;
  const int bk = blockIdx.y;
  const f16_t* src = vn + ((size_t)bk * 2048 + t0) * 128;
  f16_t* dst = vt + (size_t)bk * 128 * 2048;
  const int tid = threadIdx.x;
#pragma unroll
  for (int it = 0; it < 4; ++it) {
    const int cch = tid + it * 256;
    const int r = cch >> 4, c = cch & 15;
    *reinterpret_cast<f16x8*>(&lsT[r * 136 + c * 8]) =
        *reinterpret_cast<const f16x8*>(src + (size_t)r * 128 + c * 8);
  }
  __syncthreads();
#pragma unroll
  for (int it = 0; it < 4; ++it) {
    const int u = tid + it * 256;
    const int d = u >> 3, c8 = u & 7;
    f16_t vals[8];
#pragma unroll
    for (int j = 0; j < 8; ++j) vals[j] = lsT[(c8 * 8 + j) * 136 + d];
    *reinterpret_cast<f16x8*>(dst + (size_t)d * 2048 + t0 + c8 * 8) =
        *reinterpret_cast<const f16x8*>(vals);
  }
}

// ---------------------------------------------------------------------------
// 256 x (64*NBU) NT GEMM, fp16 in, OutT out (R10/R11 proven).
// 1024 threads = 16 waves (4M x 4N); BK=64; 2-phase counted-vmcnt.
// ---------------------------------------------------------------------------
template <int NBU, typename OutT>
__global__ __launch_bounds__(1024, 1) void k_gemmQ(
    const f16_t* __restrict__ A, const f16_t* __restrict__ Bm,
    OutT* __restrict__ C, int M, int N, int K, int lda, int ldb)
{
  __shared__ __align__(16) f16_t lds[2][(4 + NBU) * 4096];
  const int tid = threadIdx.x;
  const int l = tid & 63, w = tid >> 6;       // w 0..15
  const int lrow = l & 15, lk = l >> 4;
  const int wm = w >> 2, wn = w & 3;          // 4 x 4 wave grid

  const int nwg = gridDim.x * gridDim.y;
  int lin = blockIdx.y * gridDim.x + blockIdx.x;
  lin = (lin & 7) * (nwg >> 3) + (lin >> 3);
  const int m0 = (lin / gridDim.x) * 256, n0 = (lin % gridDim.x) * (64 * NBU);

  const bool stager = (tid < 512);
  const int srow = tid >> 3;
  const int scol = ((tid & 7) ^ (srow & 7)) << 3;
  const f16_t* gP[4 + NBU];
#pragma unroll
  for (int u = 0; u < 4; ++u) gP[u] = A + (size_t)(m0 + u * 64 + srow) * lda + scol;
#pragma unroll
  for (int u = 0; u < NBU; ++u) gP[4 + u] = Bm + (size_t)(n0 + u * 64 + srow) * ldb + scol;

  auto stageAll = [&](int buf, int k0) {
#pragma unroll
    for (int u = 0; u < 4 + NBU; ++u)
      gload16(gP[u] + k0, &lds[buf][u * 4096 + tid * 8]);
  };
  auto rdA = [&](int buf, int mf, int ks) -> f16x8 {
    const int row = wm * 64 + mf * 16 + lrow;             // 0..255
    const int slot = ((ks << 2) | lk) ^ (row & 7);
    return *reinterpret_cast<const f16x8*>(&lds[buf][row * 64 + slot * 8]);
  };
  auto rdB = [&](int buf, int nf, int ks) -> f16x8 {
    const int row = wn * (16 * NBU) + nf * 16 + lrow;     // 0..64*NBU-1
    const int slot = ((ks << 2) | lk) ^ (row & 7);
    return *reinterpret_cast<const f16x8*>(&lds[buf][16384 + row * 64 + slot * 8]);
  };

  f32x4 acc[4][NBU] = {};
  const int nkt = K >> 6;

  if (stager) {
    stageAll(0, 0);
    stageAll(1, nkt > 1 ? 64 : 0);
  }
  if constexpr (NBU == 3) { asm volatile("s_waitcnt vmcnt(7)" ::: "memory"); }
  else                    { asm volatile("s_waitcnt vmcnt(6)" ::: "memory"); }
  SCHED0();
  SBAR(); SCHED0();

  f16x8 aA[4][2], bB[NBU][2];
  for (int kt = 0; kt < nkt; ++kt) {
    const int b = kt & 1;
    const int kn2 = (kt + 2 < nkt ? kt + 2 : nkt - 1) << 6;

    // phase 1: read all frags of tile t, MFMA mf 0..1
#pragma unroll
    for (int mf = 0; mf < 4; ++mf) { aA[mf][0] = rdA(b, mf, 0); aA[mf][1] = rdA(b, mf, 1); }
#pragma unroll
    for (int nf = 0; nf < NBU; ++nf) { bB[nf][0] = rdB(b, nf, 0); bB[nf][1] = rdB(b, nf, 1); }
    __builtin_amdgcn_s_setprio(1);
#pragma unroll
    for (int mf = 0; mf < 2; ++mf)
#pragma unroll
      for (int nf = 0; nf < NBU; ++nf)
#pragma unroll
        for (int ks = 0; ks < 2; ++ks)
          acc[mf][nf] = MFMA16F(aA[mf][ks], bB[nf][ks], acc[mf][nf]);
    __builtin_amdgcn_s_setprio(0);
    LGKM0(); SCHED0();
    SBAR(); SCHED0();

    // phase 2: stage tile t+2 over dead buf b; wait tile t+1; MFMA mf 2..3
    if (stager) stageAll(b, kn2);
    if constexpr (NBU == 3) { asm volatile("s_waitcnt vmcnt(7)" ::: "memory"); }
    else                    { asm volatile("s_waitcnt vmcnt(6)" ::: "memory"); }
    SCHED0();
    __builtin_amdgcn_s_setprio(1);
#pragma unroll
    for (int mf = 2; mf < 4; ++mf)
#pragma unroll
      for (int nf = 0; nf < NBU; ++nf)
#pragma unroll
        for (int ks = 0; ks < 2; ++ks)
          acc[mf][nf] = MFMA16F(aA[mf][ks], bB[nf][ks], acc[mf][nf]);
    __builtin_amdgcn_s_setprio(0);
    SBAR(); SCHED0();
  }

  // C-write
#pragma unroll
  for (int mf = 0; mf < 4; ++mf) {
    const int row = m0 + wm * 64 + mf * 16 + lk * 4;
#pragma unroll
    for (int nf = 0; nf < NBU; ++nf) {
      const int col = n0 + wn * (16 * NBU) + nf * 16 + lrow;
#pragma unroll
      for (int rg = 0; rg < 4; ++rg)
        C[(size_t)(row + rg) * N + col] = (OutT)acc[mf][nf][rg];
    }
  }
  (void)M;
}

// ---------------------------------------------------------------------------
// QKV epilogue (unchanged from R11).
// ---------------------------------------------------------------------------
__global__ __launch_bounds__(256) void k_qkv_epi(
    const f16_t* __restrict__ qkv, const float* __restrict__ ve,
    const float* __restrict__ qgain,
    const float* __restrict__ ctab, const float* __restrict__ stab,
    f16_t* __restrict__ qn, f16_t* __restrict__ kn, f16_t* __restrict__ vn)
{
  const int blk = blockIdx.x;           // b*2048 + t
  const int b = blk >> 11, t = blk & 2047;
  const int w = threadIdx.x >> 6, l = threadIdx.x & 63;
  const int i32 = l & 31;
  const float c = ctab[t * 32 + i32], s = stab[t * 32 + i32];
  const float EPS = 1.1920929e-07f;
  constexpr float SCALE_L2E = 0.088388347648318447f * 1.4426950408889634f;

#pragma unroll
  for (int it = 0; it < 4; ++it) {
    const int h = w + it * 4;
    const f16_t* row = qkv + (size_t)blk * 3072 + h * 128;
    float x0 = (float)row[l], x1 = (float)row[l + 64];
    float ss = x0 * x0 + x1 * x1;
#pragma unroll
    for (int off = 32; off; off >>= 1) ss += __shfl_xor(ss, off);
    const float rn = rsqrtf(ss * (1.0f / 128.0f) + EPS);
    x0 *= rn; x1 *= rn;
    const float p = __shfl_xor(x0, 32);
    float xr = (l < 32) ? (x0 * c - p * s) : (p * s + x0 * c);
    const float g = qgain[h] * SCALE_L2E;
    xr *= g; x1 *= g;
    f16_t* orow = qn + (((size_t)(b * 16 + h)) * 2048 + t) * 128;
    orow[l] = (f16_t)xr;
    orow[l + 64] = (f16_t)x1;
  }
  {
    const f16_t* row = qkv + (size_t)blk * 3072 + 2048 + w * 128;
    float x0 = (float)row[l], x1 = (float)row[l + 64];
    float ss = x0 * x0 + x1 * x1;
#pragma unroll
    for (int off = 32; off; off >>= 1) ss += __shfl_xor(ss, off);
    const float rn = rsqrtf(ss * (1.0f / 128.0f) + EPS);
    x0 *= rn; x1 *= rn;
    const float p = __shfl_xor(x0, 32);
    const float xr = (l < 32) ? (x0 * c - p * s) : (p * s + x0 * c);
    f16_t* orow = kn + (((size_t)(b * 4 + w)) * 2048 + t) * 128;
    orow[l] = (f16_t)xr;
    orow[l + 64] = (f16_t)x1;
  }
  {
    const f16_t* row = qkv + (size_t)blk * 3072 + 2560 + w * 128;
    const float* verow = ve + (size_t)blk * 512 + w * 128;
    f16_t* orow = vn + (((size_t)(b * 4 + w)) * 2048 + t) * 128;
    orow[l] = (f16_t)((float)row[l] + verow[l]);
    orow[l + 64] = (f16_t)((float)row[l + 64] + verow[l + 64]);
  }
}

// ---------------------------------------------------------------------------
// Causal GQA flash attention, fp16, swapped QK^T (S^T = mfma(K,Q)): lane
// holds S[q=lrow][kv=cf*16+lk*4+rg] -> lane-local softmax.  QBLK=64 (4 waves
// x 16 q-rows), KVBLK=64, longest-qt-first.  LDS (XOR-swizzled, 40960B):
// lsK [64][128], lsV^T [128][64], lsP [4][16][64].  lb(256,3): VGPR ~100,
// no spill (R14's lb(256,4) capped at 64 -> 110MB scratch writes).
// ---------------------------------------------------------------------------
__global__ __launch_bounds__(256, 3) void k_attn(
    const f16_t* __restrict__ qn, const f16_t* __restrict__ kn,
    const f16_t* __restrict__ vt, f16_t* __restrict__ y)
{
  __shared__ __align__(16) f16_t lsK[64 * 128];      // 16384 B
  __shared__ __align__(16) f16_t lsV[128 * 64];      // 16384 B
  __shared__ __align__(16) f16_t lsPb[4][16 * 64];   //  8192 B
  const int qt = 31 - (int)blockIdx.y;  // longest first
  const int bh = blockIdx.x;            // 0..31
  const int b = bh >> 4, h = bh & 15, kvh = h >> 2;
  const int tid = threadIdx.x, w = tid >> 6, l = tid & 63;
  const int lrow = l & 15, lk = l >> 4;
  const int qbase = qt * 64 + w * 16;
  constexpr float NEG = -1e30f;
  f16_t* lsP = lsPb[w];

  // Q fragments (row/col = lane&15, k = lk*8+j)
  const f16_t* qp = qn + ((size_t)(b * 16 + h) * 2048) * 128;
  f16x8 aQ[4];
#pragma unroll
  for (int kf = 0; kf < 4; ++kf)
    aQ[kf] = *reinterpret_cast<const f16x8*>(
        qp + (size_t)(qbase + lrow) * 128 + kf * 32 + lk * 8);

  const f16_t* kp = kn + ((size_t)(b * 4 + kvh) * 2048) * 128;
  const f16_t* vtp = vt + (size_t)(b * 4 + kvh) * 128 * 2048;

  f32x4 o[8] = {};
  float mst = NEG;   // running max for THIS LANE's q-row (q = lrow)
  float lst = 0.f;   // per-lane partial sum for q = lrow (reduced at end)

  f16x8 kreg[4], vreg[4];
  auto loadKV = [&](int t0) {
#pragma unroll
    for (int it = 0; it < 4; ++it) {
      const int cch = tid + it * 256;
      kreg[it] = *reinterpret_cast<const f16x8*>(
          kp + (size_t)(t0 + (cch >> 4)) * 128 + (cch & 15) * 8);
      vreg[it] = *reinterpret_cast<const f16x8*>(
          vtp + (size_t)(cch >> 3) * 2048 + t0 + (cch & 7) * 8);
    }
  };
  loadKV(0);

  const int ntiles = qt + 1;
  for (int tt = 0; tt < ntiles; ++tt) {
    __syncthreads();  // prior tile's K/V LDS reads done before restage
    // stage K [64][128] slot^=(r&7); V^T [128][64] slot^=((d>>3)&7); all b128
#pragma unroll
    for (int it = 0; it < 4; ++it) {
      const int cch = tid + it * 256;
      const int r = cch >> 4, dg = cch & 15;
      *reinterpret_cast<f16x8*>(&lsK[r * 128 + ((dg ^ (r & 7)) << 3)]) = kreg[it];
      const int d = cch >> 3, c8 = cch & 7;
      *reinterpret_cast<f16x8*>(&lsV[d * 64 + ((c8 ^ ((d >> 3) & 7)) << 3)]) = vreg[it];
    }
    if (tt + 1 < ntiles) loadKV((tt + 1) * 64);
    __syncthreads();  // staged data visible

    // S^T = K Q^T: sacc[cf][rg] = S[q=lrow][kv = cf*16 + lk*4 + rg]
    f32x4 sacc[4] = {};
#pragma unroll
    for (int cf = 0; cf < 4; ++cf) {
      const int krow = cf * 16 + lrow;
#pragma unroll
      for (int kf = 0; kf < 4; ++kf) {
        const f16x8 aK = *reinterpret_cast<const f16x8*>(
            &lsK[krow * 128 + ((((kf << 2) | lk) ^ (krow & 7)) << 3)]);
        sacc[cf] = MFMA16F(aK, aQ[kf], sacc[cf]);
      }
    }

    // mask (diagonal tile only): kv_in_tile > q_in_block
    if (tt == qt) {
      const int qin = w * 16 + lrow;
#pragma unroll
      for (int cf = 0; cf < 4; ++cf)
#pragma unroll
        for (int rg = 0; rg < 4; ++rg)
          if (cf * 16 + lk * 4 + rg > qin) sacc[cf][rg] = NEG;
    }

    // lane-local max of this tile's 16 values
    float mx = NEG;
#pragma unroll
    for (int cf = 0; cf < 4; ++cf)
      mx = fmaxf(mx, fmaxf(fmaxf(sacc[cf][0], sacc[cf][1]),
                           fmaxf(sacc[cf][2], sacc[cf][3])));
    if (__any(mx > mst + 8.f)) {
      // row-consistent new max over the 4 lk-lanes holding this q-row
      float rmx = mx;
      rmx = fmaxf(rmx, __shfl_xor(rmx, 16));
      rmx = fmaxf(rmx, __shfl_xor(rmx, 32));
      const float mnew = fmaxf(mst, rmx);
      const float alpha = exp2f(mst - mnew);
      mst = mnew;
      lst *= alpha;
      // o rows are q = lk*4+rg; fetch that row's alpha from lane (lk*4+rg)
#pragma unroll
      for (int rg = 0; rg < 4; ++rg) {
        const float arow = __shfl(alpha, lk * 4 + rg);
#pragma unroll
        for (int df = 0; df < 8; ++df) o[df][rg] *= arow;
      }
    }
    // P = exp2(S - mst), lane-local partial sum
#pragma unroll
    for (int cf = 0; cf < 4; ++cf) {
#pragma unroll
      for (int rg = 0; rg < 4; ++rg) {
        const float p = exp2f(sacc[cf][rg] - mst);
        sacc[cf][rg] = p;
        lst += p;
      }
    }

    // P -> LDS [q=16][kv=64], b64 per cf (kv = cf*16+lk*4 .. +3), XOR slot8
#pragma unroll
    for (int cf = 0; cf < 4; ++cf) {
      f16x4 pk;
#pragma unroll
      for (int rg = 0; rg < 4; ++rg) pk[rg] = (f16_t)sacc[cf][rg];
      const int slot8 = cf * 2 + (lk >> 1);
      *reinterpret_cast<f16x4*>(
          &lsP[lrow * 64 + ((slot8 ^ (lrow & 7)) << 3) + (lk & 1) * 4]) = pk;
    }
    // PV: aP = P[q=lrow][kv=k2*32+lk*8+j]; bV = V[kv][d=df*16+lrow]
#pragma unroll
    for (int k2 = 0; k2 < 2; ++k2) {
      const f16x8 aP = *reinterpret_cast<const f16x8*>(
          &lsP[lrow * 64 + ((((k2 << 2) | lk) ^ (lrow & 7)) << 3)]);
#pragma unroll
      for (int df = 0; df < 8; ++df) {
        const int row = df * 16 + lrow;
        const f16x8 bV = *reinterpret_cast<const f16x8*>(
            &lsV[row * 64 + ((((k2 << 2) | lk) ^ ((row >> 3) & 7)) << 3)]);
        o[df] = MFMA16F(aP, bV, o[df]);
      }
    }
  }

  // reduce lst over the 4 lk-lanes of each q-row (all 4 copies equal after)
  lst += __shfl_xor(lst, 16);
  lst += __shfl_xor(lst, 32);

  // normalize + write y: o[df][rg] is q = lk*4+rg, d = df*16+lrow
#pragma unroll
  for (int rg = 0; rg < 4; ++rg) {
    const float lrow_sum = __shfl(lst, lk * 4 + rg);
    const float inv = 1.0f / lrow_sum;
    const int qi = qbase + lk * 4 + rg;
    const size_t rowoff = ((size_t)(b * 2048 + qi)) * 2048 + h * 128;
#pragma unroll
    for (int df = 0; df < 8; ++df)
      y[rowoff + df * 16 + lrow] = (f16_t)(o[df][rg] * inv);
  }
}

// ---------------------------------------------------------------------------
extern "C" void kernel_launch(void* const* d_in, const int* in_sizes, int n_in,
                              void* d_out, int out_size, void* d_ws, size_t ws_size,
                              hipStream_t stream) {
  const float* x  = (const float*)d_in[0];
  const float* ve = (const float*)d_in[1];
  const float* Wq = (const float*)d_in[2];
  const float* Wk = (const float*)d_in[3];
  const float* Wv = (const float*)d_in[4];
  const float* Wp = (const float*)d_in[5];
  const float* qg = (const float*)d_in[6];
  float* out = (float*)d_out;

  char* ws = (char*)d_ws;
  size_t off = 0;
  auto alloc = [&](size_t bytes) -> char* {
    char* p = ws + off;
    off += (bytes + 255) & ~(size_t)255;
    return p;
  };

  f16_t* xf    = (f16_t*)alloc((size_t)4096 * 2048 * 2);   // later qn
  f16_t* wqkvf = (f16_t*)alloc((size_t)3072 * 2048 * 2);   // rows Wq|Wk|Wv
  f16_t* wpf   = (f16_t*)alloc((size_t)2048 * 2048 * 2);
  f16_t* qkvf  = (f16_t*)alloc((size_t)4096 * 3072 * 2);   // GEMM out; later yb
  f16_t* kn    = (f16_t*)alloc((size_t)2 * 4 * 2048 * 128 * 2);
  f16_t* vn    = (f16_t*)alloc((size_t)2 * 4 * 2048 * 128 * 2);
  f16_t* vt    = (f16_t*)alloc((size_t)2 * 4 * 128 * 2048 * 2);
  float* ctab  = (float*)alloc((size_t)2048 * 32 * 4);
  float* stab  = (float*)alloc((size_t)2048 * 32 * 4);
  f16_t* qn    = xf;      // xf dead after QKV GEMM
  f16_t* yb    = qkvf;    // qkvf dead after epilogue
  (void)ws_size; (void)in_sizes; (void)n_in; (void)out_size;

  k_cast_f16<<<1024, 256, 0, stream>>>(x, xf, (long)4096 * 2048);
  k_cast_wqkv<<<1536, 256, 0, stream>>>(Wq, Wk, Wv, wqkvf);
  k_cast_f16<<<1024, 256, 0, stream>>>(Wp, wpf, (long)2048 * 2048);
  k_rope_tab<<<256, 256, 0, stream>>>(ctab, stab);

  // qkvf = x·[Wq|Wk|Wv]^T  (M=4096 N=3072 K=2048; 256x192 tiles, grid 16x16)
  k_gemmQ<3, f16_t><<<dim3(16, 16), 1024, 0, stream>>>(
      xf, wqkvf, qkvf, 4096, 3072, 2048, 2048, 2048);

  k_qkv_epi<<<4096, 256, 0, stream>>>(qkvf, ve, qg, ctab, stab, qn, kn, vn);

  k_vtrans<<<dim3(32, 8), 256, 0, stream>>>(vn, vt);

  k_attn<<<dim3(32, 32), 256, 0, stream>>>(qn, kn, vt, yb);

  // out = y · Wp^T  (M=4096 N=2048 K=2048; 256x128 tiles, grid 16x16)
  k_gemmQ<2, float><<<dim3(16, 16), 1024, 0, stream>>>(
      yb, wpf, out, 4096, 2048, 2048, 2048, 2048);
}

// Round 16
// 198.518 us; speedup vs baseline: 1.7358x; 1.0427x over previous
//
#include <hip/hip_runtime.h>
#include <hip/hip_bf16.h>
#include <cstdint>
#include <cstddef>

// ---------------------------------------------------------------------------
// CausalSelfAttention fused block, MI355X/gfx950.  Round 16:
//  - attn: V-swizzle key fixed ((row>>3)&7 -> row&7: R15's key collapsed bV
//    reads into half the bank groups -> 2x LDS cycles on the biggest term);
//    QBLK=128 w/ 2 q-frags per wave: aK/bV LDS reads amortized over 32 q-rows
//    (traffic per q halves); lb(256,2); fully-masked waves skip compute.
//  - GEMMs/epilogue/vtrans unchanged.
// B=2 T=2048 D=2048 NH=16 NKV=4 HD=128 ROPE=64.
// ---------------------------------------------------------------------------

typedef _Float16 f16_t;
typedef f16_t f16x4 __attribute__((ext_vector_type(4)));
typedef f16_t f16x8 __attribute__((ext_vector_type(8)));
typedef float f32x4 __attribute__((ext_vector_type(4)));

#define MFMA16F(a, b, c) __builtin_amdgcn_mfma_f32_16x16x32_f16((a), (b), (c), 0, 0, 0)
#define SBAR()   __builtin_amdgcn_s_barrier()
#define SCHED0() __builtin_amdgcn_sched_barrier(0)
#define LGKM0()  asm volatile("s_waitcnt lgkmcnt(0)" ::: "memory")

__device__ __forceinline__ void gload16(const f16_t* g, f16_t* l) {
  auto lds_ptr = reinterpret_cast<__attribute__((address_space(3))) unsigned int*>(
      reinterpret_cast<uintptr_t>(l));
  auto g_ptr = reinterpret_cast<const __attribute__((address_space(1))) unsigned int*>(
      reinterpret_cast<uintptr_t>(g));
  __builtin_amdgcn_global_load_lds(g_ptr, lds_ptr, 16, 0, 0);
}

// ---------------------------------------------------------------------------
// fp32 -> fp16 cast, vectorized
// ---------------------------------------------------------------------------
__global__ void k_cast_f16(const float* __restrict__ in, f16_t* __restrict__ o, long n) {
  long i = ((long)blockIdx.x * blockDim.x + threadIdx.x) * 4;
  const long step = (long)gridDim.x * blockDim.x * 4;
  for (; i < n; i += step) {
    const float4 v = *reinterpret_cast<const float4*>(in + i);
    f16_t r[4] = {(f16_t)v.x, (f16_t)v.y, (f16_t)v.z, (f16_t)v.w};
    *reinterpret_cast<uint64_t*>(o + i) = *reinterpret_cast<const uint64_t*>(r);
  }
}

// ---------------------------------------------------------------------------
// merged W cast: rows 0-2047 Wq, 2048-2559 Wk, 2560-3071 Wv -> wf [3072][2048]
// ---------------------------------------------------------------------------
__global__ void k_cast_wqkv(const float* __restrict__ Wq, const float* __restrict__ Wk,
                            const float* __restrict__ Wv, f16_t* __restrict__ wf) {
  long i = ((long)blockIdx.x * blockDim.x + threadIdx.x) * 4;
  const long step = (long)gridDim.x * blockDim.x * 4;
  for (; i < (long)3072 * 2048; i += step) {
    const long row = i >> 11, col = i & 2047;
    const float* src = (row < 2048) ? (Wq + (size_t)row * 2048)
                     : (row < 2560) ? (Wk + (size_t)(row - 2048) * 2048)
                                    : (Wv + (size_t)(row - 2560) * 2048);
    const float4 v = *reinterpret_cast<const float4*>(src + col);
    f16_t r[4] = {(f16_t)v.x, (f16_t)v.y, (f16_t)v.z, (f16_t)v.w};
    *reinterpret_cast<uint64_t*>(wf + row * 2048 + col) = *reinterpret_cast<const uint64_t*>(r);
  }
}

// ---------------------------------------------------------------------------
// RoPE cos/sin table: [T=2048][32]
// ---------------------------------------------------------------------------
__global__ void k_rope_tab(float* __restrict__ ctab, float* __restrict__ stab) {
  const int idx = blockIdx.x * blockDim.x + threadIdx.x;
  if (idx >= 2048 * 32) return;
  const int t = idx >> 5, i = idx & 31;
  const float freq = exp2f(-(float)i * 0.2076205059304601f);  // 10000^(-i/64)
  const float f = (float)t * freq;
  ctab[idx] = cosf(f);
  stab[idx] = sinf(f);
}

// ---------------------------------------------------------------------------
// V transpose: vn [bk][2048 t][128 d] -> vt [bk][128 d][2048 t].
// ---------------------------------------------------------------------------
__global__ __launch_bounds__(256) void k_vtrans(
    const f16_t* __restrict__ vn, f16_t* __restrict__ vt)
{
  __shared__ __align__(16) f16_t lsT[64 * 136];
  const int t0 = blockIdx.x * 64;
  const int bk = blockIdx.y;
  const f16_t* src = vn + ((size_t)bk * 2048 + t0) * 128;
  f16_t* dst = vt + (size_t)bk * 128 * 2048;
  const int tid = threadIdx.x;
#pragma unroll
  for (int it = 0; it < 4; ++it) {
    const int cch = tid + it * 256;
    const int r = cch >> 4, c = cch & 15;
    *reinterpret_cast<f16x8*>(&lsT[r * 136 + c * 8]) =
        *reinterpret_cast<const f16x8*>(src + (size_t)r * 128 + c * 8);
  }
  __syncthreads();
#pragma unroll
  for (int it = 0; it < 4; ++it) {
    const int u = tid + it * 256;
    const int d = u >> 3, c8 = u & 7;
    f16_t vals[8];
#pragma unroll
    for (int j = 0; j < 8; ++j) vals[j] = lsT[(c8 * 8 + j) * 136 + d];
    *reinterpret_cast<f16x8*>(dst + (size_t)d * 2048 + t0 + c8 * 8) =
        *reinterpret_cast<const f16x8*>(vals);
  }
}

// ---------------------------------------------------------------------------
// 256 x (64*NBU) NT GEMM, fp16 in, OutT out (R10/R11 proven).
// 1024 threads = 16 waves (4M x 4N); BK=64; 2-phase counted-vmcnt.
// ---------------------------------------------------------------------------
template <int NBU, typename OutT>
__global__ __launch_bounds__(1024, 1) void k_gemmQ(
    const f16_t* __restrict__ A, const f16_t* __restrict__ Bm,
    OutT* __restrict__ C, int M, int N, int K, int lda, int ldb)
{
  __shared__ __align__(16) f16_t lds[2][(4 + NBU) * 4096];
  const int tid = threadIdx.x;
  const int l = tid & 63, w = tid >> 6;       // w 0..15
  const int lrow = l & 15, lk = l >> 4;
  const int wm = w >> 2, wn = w & 3;          // 4 x 4 wave grid

  const int nwg = gridDim.x * gridDim.y;
  int lin = blockIdx.y * gridDim.x + blockIdx.x;
  lin = (lin & 7) * (nwg >> 3) + (lin >> 3);
  const int m0 = (lin / gridDim.x) * 256, n0 = (lin % gridDim.x) * (64 * NBU);

  const bool stager = (tid < 512);
  const int srow = tid >> 3;
  const int scol = ((tid & 7) ^ (srow & 7)) << 3;
  const f16_t* gP[4 + NBU];
#pragma unroll
  for (int u = 0; u < 4; ++u) gP[u] = A + (size_t)(m0 + u * 64 + srow) * lda + scol;
#pragma unroll
  for (int u = 0; u < NBU; ++u) gP[4 + u] = Bm + (size_t)(n0 + u * 64 + srow) * ldb + scol;

  auto stageAll = [&](int buf, int k0) {
#pragma unroll
    for (int u = 0; u < 4 + NBU; ++u)
      gload16(gP[u] + k0, &lds[buf][u * 4096 + tid * 8]);
  };
  auto rdA = [&](int buf, int mf, int ks) -> f16x8 {
    const int row = wm * 64 + mf * 16 + lrow;             // 0..255
    const int slot = ((ks << 2) | lk) ^ (row & 7);
    return *reinterpret_cast<const f16x8*>(&lds[buf][row * 64 + slot * 8]);
  };
  auto rdB = [&](int buf, int nf, int ks) -> f16x8 {
    const int row = wn * (16 * NBU) + nf * 16 + lrow;     // 0..64*NBU-1
    const int slot = ((ks << 2) | lk) ^ (row & 7);
    return *reinterpret_cast<const f16x8*>(&lds[buf][16384 + row * 64 + slot * 8]);
  };

  f32x4 acc[4][NBU] = {};
  const int nkt = K >> 6;

  if (stager) {
    stageAll(0, 0);
    stageAll(1, nkt > 1 ? 64 : 0);
  }
  if constexpr (NBU == 3) { asm volatile("s_waitcnt vmcnt(7)" ::: "memory"); }
  else                    { asm volatile("s_waitcnt vmcnt(6)" ::: "memory"); }
  SCHED0();
  SBAR(); SCHED0();

  f16x8 aA[4][2], bB[NBU][2];
  for (int kt = 0; kt < nkt; ++kt) {
    const int b = kt & 1;
    const int kn2 = (kt + 2 < nkt ? kt + 2 : nkt - 1) << 6;

    // phase 1: read all frags of tile t, MFMA mf 0..1
#pragma unroll
    for (int mf = 0; mf < 4; ++mf) { aA[mf][0] = rdA(b, mf, 0); aA[mf][1] = rdA(b, mf, 1); }
#pragma unroll
    for (int nf = 0; nf < NBU; ++nf) { bB[nf][0] = rdB(b, nf, 0); bB[nf][1] = rdB(b, nf, 1); }
    __builtin_amdgcn_s_setprio(1);
#pragma unroll
    for (int mf = 0; mf < 2; ++mf)
#pragma unroll
      for (int nf = 0; nf < NBU; ++nf)
#pragma unroll
        for (int ks = 0; ks < 2; ++ks)
          acc[mf][nf] = MFMA16F(aA[mf][ks], bB[nf][ks], acc[mf][nf]);
    __builtin_amdgcn_s_setprio(0);
    LGKM0(); SCHED0();
    SBAR(); SCHED0();

    // phase 2: stage tile t+2 over dead buf b; wait tile t+1; MFMA mf 2..3
    if (stager) stageAll(b, kn2);
    if constexpr (NBU == 3) { asm volatile("s_waitcnt vmcnt(7)" ::: "memory"); }
    else                    { asm volatile("s_waitcnt vmcnt(6)" ::: "memory"); }
    SCHED0();
    __builtin_amdgcn_s_setprio(1);
#pragma unroll
    for (int mf = 2; mf < 4; ++mf)
#pragma unroll
      for (int nf = 0; nf < NBU; ++nf)
#pragma unroll
        for (int ks = 0; ks < 2; ++ks)
          acc[mf][nf] = MFMA16F(aA[mf][ks], bB[nf][ks], acc[mf][nf]);
    __builtin_amdgcn_s_setprio(0);
    SBAR(); SCHED0();
  }

  // C-write
#pragma unroll
  for (int mf = 0; mf < 4; ++mf) {
    const int row = m0 + wm * 64 + mf * 16 + lk * 4;
#pragma unroll
    for (int nf = 0; nf < NBU; ++nf) {
      const int col = n0 + wn * (16 * NBU) + nf * 16 + lrow;
#pragma unroll
      for (int rg = 0; rg < 4; ++rg)
        C[(size_t)(row + rg) * N + col] = (OutT)acc[mf][nf][rg];
    }
  }
  (void)M;
}

// ---------------------------------------------------------------------------
// QKV epilogue (unchanged from R11).
// ---------------------------------------------------------------------------
__global__ __launch_bounds__(256) void k_qkv_epi(
    const f16_t* __restrict__ qkv, const float* __restrict__ ve,
    const float* __restrict__ qgain,
    const float* __restrict__ ctab, const float* __restrict__ stab,
    f16_t* __restrict__ qn, f16_t* __restrict__ kn, f16_t* __restrict__ vn)
{
  const int blk = blockIdx.x;           // b*2048 + t
  const int b = blk >> 11, t = blk & 2047;
  const int w = threadIdx.x >> 6, l = threadIdx.x & 63;
  const int i32 = l & 31;
  const float c = ctab[t * 32 + i32], s = stab[t * 32 + i32];
  const float EPS = 1.1920929e-07f;
  constexpr float SCALE_L2E = 0.088388347648318447f * 1.4426950408889634f;

#pragma unroll
  for (int it = 0; it < 4; ++it) {
    const int h = w + it * 4;
    const f16_t* row = qkv + (size_t)blk * 3072 + h * 128;
    float x0 = (float)row[l], x1 = (float)row[l + 64];
    float ss = x0 * x0 + x1 * x1;
#pragma unroll
    for (int off = 32; off; off >>= 1) ss += __shfl_xor(ss, off);
    const float rn = rsqrtf(ss * (1.0f / 128.0f) + EPS);
    x0 *= rn; x1 *= rn;
    const float p = __shfl_xor(x0, 32);
    float xr = (l < 32) ? (x0 * c - p * s) : (p * s + x0 * c);
    const float g = qgain[h] * SCALE_L2E;
    xr *= g; x1 *= g;
    f16_t* orow = qn + (((size_t)(b * 16 + h)) * 2048 + t) * 128;
    orow[l] = (f16_t)xr;
    orow[l + 64] = (f16_t)x1;
  }
  {
    const f16_t* row = qkv + (size_t)blk * 3072 + 2048 + w * 128;
    float x0 = (float)row[l], x1 = (float)row[l + 64];
    float ss = x0 * x0 + x1 * x1;
#pragma unroll
    for (int off = 32; off; off >>= 1) ss += __shfl_xor(ss, off);
    const float rn = rsqrtf(ss * (1.0f / 128.0f) + EPS);
    x0 *= rn; x1 *= rn;
    const float p = __shfl_xor(x0, 32);
    const float xr = (l < 32) ? (x0 * c - p * s) : (p * s + x0 * c);
    f16_t* orow = kn + (((size_t)(b * 4 + w)) * 2048 + t) * 128;
    orow[l] = (f16_t)xr;
    orow[l + 64] = (f16_t)x1;
  }
  {
    const f16_t* row = qkv + (size_t)blk * 3072 + 2560 + w * 128;
    const float* verow = ve + (size_t)blk * 512 + w * 128;
    f16_t* orow = vn + (((size_t)(b * 4 + w)) * 2048 + t) * 128;
    orow[l] = (f16_t)((float)row[l] + verow[l]);
    orow[l + 64] = (f16_t)((float)row[l + 64] + verow[l + 64]);
  }
}

// ---------------------------------------------------------------------------
// Causal GQA flash attention, fp16, swapped QK^T, QBLK=128 (4 waves x 32
// q-rows, 2 q-frags/wave sharing aK/bV LDS reads).  KVBLK=64,
// longest-qt-first (qt 0..15, ntiles = 2qt+2).
// LDS (XOR-swizzled, 48KB): lsK [64][128] key r&7; lsV^T [128][64] key d&7
// (full 8-group spread on both sides); lsP [4][2][16][64].
// lb(256,2): VGPR <=256, 2 blocks/CU.
// ---------------------------------------------------------------------------
__global__ __launch_bounds__(256, 2) void k_attn(
    const f16_t* __restrict__ qn, const f16_t* __restrict__ kn,
    const f16_t* __restrict__ vt, f16_t* __restrict__ y)
{
  __shared__ __align__(16) f16_t lsK[64 * 128];         // 16384 B
  __shared__ __align__(16) f16_t lsV[128 * 64];         // 16384 B
  __shared__ __align__(16) f16_t lsPb[4][2][16 * 64];   // 16384 B
  const int qt = 15 - (int)blockIdx.y;  // longest first
  const int bh = blockIdx.x;            // 0..31
  const int b = bh >> 4, h = bh & 15, kvh = h >> 2;
  const int tid = threadIdx.x, w = tid >> 6, l = tid & 63;
  const int lrow = l & 15, lk = l >> 4;
  const int qbase = qt * 128 + w * 32;
  constexpr float NEG = -1e30f;

  // Q fragments as B-operand (col = lane&15, k = lk*8+j), 2 q-frags
  const f16_t* qp = qn + ((size_t)(b * 16 + h) * 2048) * 128;
  f16x8 bQ[2][4];
#pragma unroll
  for (int qf = 0; qf < 2; ++qf)
#pragma unroll
    for (int kf = 0; kf < 4; ++kf)
      bQ[qf][kf] = *reinterpret_cast<const f16x8*>(
          qp + (size_t)(qbase + qf * 16 + lrow) * 128 + kf * 32 + lk * 8);

  const f16_t* kp = kn + ((size_t)(b * 4 + kvh) * 2048) * 128;
  const f16_t* vtp = vt + (size_t)(b * 4 + kvh) * 128 * 2048;

  f32x4 o0[8] = {}, o1[8] = {};
  float mst0 = NEG, mst1 = NEG, lst0 = 0.f, lst1 = 0.f;

  f16x8 kreg[4], vreg[4];
  auto loadKV = [&](int t0) {
#pragma unroll
    for (int it = 0; it < 4; ++it) {
      const int cch = tid + it * 256;
      kreg[it] = *reinterpret_cast<const f16x8*>(
          kp + (size_t)(t0 + (cch >> 4)) * 128 + (cch & 15) * 8);
      vreg[it] = *reinterpret_cast<const f16x8*>(
          vtp + (size_t)(cch >> 3) * 2048 + t0 + (cch & 7) * 8);
    }
  };
  loadKV(0);

  const int ntiles = 2 * qt + 2;
  for (int tt = 0; tt < ntiles; ++tt) {
    __syncthreads();  // prior tile's K/V LDS reads done before restage
    // stage K [64][128] slot^=(r&7); V^T [128][64] slot8^=(d&7); all b128
#pragma unroll
    for (int it = 0; it < 4; ++it) {
      const int cch = tid + it * 256;
      const int r = cch >> 4, dg = cch & 15;
      *reinterpret_cast<f16x8*>(&lsK[r * 128 + ((dg ^ (r & 7)) << 3)]) = kreg[it];
      const int d = cch >> 3, c8 = cch & 7;
      *reinterpret_cast<f16x8*>(&lsV[d * 64 + ((c8 ^ (d & 7)) << 3)]) = vreg[it];
    }
    if (tt + 1 < ntiles) loadKV((tt + 1) * 64);
    __syncthreads();  // staged data visible

    // tile 2qt+1 fully masks waves 0,1 (q < kv always) -> skip compute
    if (tt == 2 * qt + 1 && w < 2) continue;

    // S^T = K Q^T for both q-frags, sharing aK reads:
    // sacc{0,1}[cf][rg] = S[q = qf*16+lrow][kv = cf*16 + lk*4 + rg]
    f32x4 sacc0[4] = {}, sacc1[4] = {};
#pragma unroll
    for (int cf = 0; cf < 4; ++cf) {
      const int krow = cf * 16 + lrow;
#pragma unroll
      for (int kf = 0; kf < 4; ++kf) {
        const f16x8 aK = *reinterpret_cast<const f16x8*>(
            &lsK[krow * 128 + ((((kf << 2) | lk) ^ (krow & 7)) << 3)]);
        sacc0[cf] = MFMA16F(aK, bQ[0][kf], sacc0[cf]);
        sacc1[cf] = MFMA16F(aK, bQ[1][kf], sacc1[cf]);
      }
    }

    // mask on the two diagonal tiles: kv_local > q_local
    if (tt >= 2 * qt) {
      const int kvoff = (tt - 2 * qt) * 64;
#pragma unroll
      for (int cf = 0; cf < 4; ++cf)
#pragma unroll
        for (int rg = 0; rg < 4; ++rg) {
          const int kvl = kvoff + cf * 16 + lk * 4 + rg;
          if (kvl > w * 32 + lrow) sacc0[cf][rg] = NEG;
          if (kvl > w * 32 + 16 + lrow) sacc1[cf][rg] = NEG;
        }
    }

    // softmax per q-frag (lane-local rows), log2 domain, defer-max THR=8
#pragma unroll
    for (int qf = 0; qf < 2; ++qf) {
      f32x4* sacc = qf ? sacc1 : sacc0;
      float& mst = qf ? mst1 : mst0;
      float& lst = qf ? lst1 : lst0;
      f32x4* o = qf ? o1 : o0;

      float mx = NEG;
#pragma unroll
      for (int cf = 0; cf < 4; ++cf)
        mx = fmaxf(mx, fmaxf(fmaxf(sacc[cf][0], sacc[cf][1]),
                             fmaxf(sacc[cf][2], sacc[cf][3])));
      if (__any(mx > mst + 8.f)) {
        float rmx = mx;
        rmx = fmaxf(rmx, __shfl_xor(rmx, 16));
        rmx = fmaxf(rmx, __shfl_xor(rmx, 32));
        const float mnew = fmaxf(mst, rmx);
        const float alpha = exp2f(mst - mnew);
        mst = mnew;
        lst *= alpha;
#pragma unroll
        for (int rg = 0; rg < 4; ++rg) {
          const float arow = __shfl(alpha, lk * 4 + rg);
#pragma unroll
          for (int df = 0; df < 8; ++df) o[df][rg] *= arow;
        }
      }
#pragma unroll
      for (int cf = 0; cf < 4; ++cf) {
#pragma unroll
        for (int rg = 0; rg < 4; ++rg) {
          const float p = exp2f(sacc[cf][rg] - mst);
          sacc[cf][rg] = p;
          lst += p;
        }
      }
      // P -> LDS [16][64], b64 per cf, XOR slot8 key lrow&7
      f16_t* lsP = lsPb[w][qf];
#pragma unroll
      for (int cf = 0; cf < 4; ++cf) {
        f16x4 pk;
#pragma unroll
        for (int rg = 0; rg < 4; ++rg) pk[rg] = (f16_t)sacc[cf][rg];
        const int slot8 = cf * 2 + (lk >> 1);
        *reinterpret_cast<f16x4*>(
            &lsPb[w][qf][lrow * 64 + ((slot8 ^ (lrow & 7)) << 3) + (lk & 1) * 4]) = pk;
      }
      (void)lsP;
    }

    // PV for both q-frags, sharing bV reads
#pragma unroll
    for (int k2 = 0; k2 < 2; ++k2) {
      const int pofs = lrow * 64 + ((((k2 << 2) | lk) ^ (lrow & 7)) << 3);
      const f16x8 aP0 = *reinterpret_cast<const f16x8*>(&lsPb[w][0][pofs]);
      const f16x8 aP1 = *reinterpret_cast<const f16x8*>(&lsPb[w][1][pofs]);
#pragma unroll
      for (int df = 0; df < 8; ++df) {
        const int row = df * 16 + lrow;
        const f16x8 bV = *reinterpret_cast<const f16x8*>(
            &lsV[row * 64 + ((((k2 << 2) | lk) ^ (row & 7)) << 3)]);
        o0[df] = MFMA16F(aP0, bV, o0[df]);
        o1[df] = MFMA16F(aP1, bV, o1[df]);
      }
    }
  }

  // reduce lst over the 4 lk-lane copies of each q-row
  lst0 += __shfl_xor(lst0, 16);
  lst0 += __shfl_xor(lst0, 32);
  lst1 += __shfl_xor(lst1, 16);
  lst1 += __shfl_xor(lst1, 32);

  // normalize + write y: o{qf}[df][rg] is q = qbase+qf*16+lk*4+rg, d = df*16+lrow
#pragma unroll
  for (int qf = 0; qf < 2; ++qf) {
    const f32x4* o = qf ? o1 : o0;
    const float lstq = qf ? lst1 : lst0;
#pragma unroll
    for (int rg = 0; rg < 4; ++rg) {
      const float lrow_sum = __shfl(lstq, lk * 4 + rg);
      const float inv = 1.0f / lrow_sum;
      const int qi = qbase + qf * 16 + lk * 4 + rg;
      const size_t rowoff = ((size_t)(b * 2048 + qi)) * 2048 + h * 128;
#pragma unroll
      for (int df = 0; df < 8; ++df)
        y[rowoff + df * 16 + lrow] = (f16_t)(o[df][rg] * inv);
    }
  }
}

// ---------------------------------------------------------------------------
extern "C" void kernel_launch(void* const* d_in, const int* in_sizes, int n_in,
                              void* d_out, int out_size, void* d_ws, size_t ws_size,
                              hipStream_t stream) {
  const float* x  = (const float*)d_in[0];
  const float* ve = (const float*)d_in[1];
  const float* Wq = (const float*)d_in[2];
  const float* Wk = (const float*)d_in[3];
  const float* Wv = (const float*)d_in[4];
  const float* Wp = (const float*)d_in[5];
  const float* qg = (const float*)d_in[6];
  float* out = (float*)d_out;

  char* ws = (char*)d_ws;
  size_t off = 0;
  auto alloc = [&](size_t bytes) -> char* {
    char* p = ws + off;
    off += (bytes + 255) & ~(size_t)255;
    return p;
  };

  f16_t* xf    = (f16_t*)alloc((size_t)4096 * 2048 * 2);   // later qn
  f16_t* wqkvf = (f16_t*)alloc((size_t)3072 * 2048 * 2);   // rows Wq|Wk|Wv
  f16_t* wpf   = (f16_t*)alloc((size_t)2048 * 2048 * 2);
  f16_t* qkvf  = (f16_t*)alloc((size_t)4096 * 3072 * 2);   // GEMM out; later yb
  f16_t* kn    = (f16_t*)alloc((size_t)2 * 4 * 2048 * 128 * 2);
  f16_t* vn    = (f16_t*)alloc((size_t)2 * 4 * 2048 * 128 * 2);
  f16_t* vt    = (f16_t*)alloc((size_t)2 * 4 * 128 * 2048 * 2);
  float* ctab  = (float*)alloc((size_t)2048 * 32 * 4);
  float* stab  = (float*)alloc((size_t)2048 * 32 * 4);
  f16_t* qn    = xf;      // xf dead after QKV GEMM
  f16_t* yb    = qkvf;    // qkvf dead after epilogue
  (void)ws_size; (void)in_sizes; (void)n_in; (void)out_size;

  k_cast_f16<<<1024, 256, 0, stream>>>(x, xf, (long)4096 * 2048);
  k_cast_wqkv<<<1536, 256, 0, stream>>>(Wq, Wk, Wv, wqkvf);
  k_cast_f16<<<1024, 256, 0, stream>>>(Wp, wpf, (long)2048 * 2048);
  k_rope_tab<<<256, 256, 0, stream>>>(ctab, stab);

  // qkvf = x·[Wq|Wk|Wv]^T  (M=4096 N=3072 K=2048; 256x192 tiles, grid 16x16)
  k_gemmQ<3, f16_t><<<dim3(16, 16), 1024, 0, stream>>>(
      xf, wqkvf, qkvf, 4096, 3072, 2048, 2048, 2048);

  k_qkv_epi<<<4096, 256, 0, stream>>>(qkvf, ve, qg, ctab, stab, qn, kn, vn);

  k_vtrans<<<dim3(32, 8), 256, 0, stream>>>(vn, vt);

  k_attn<<<dim3(32, 16), 256, 0, stream>>>(qn, kn, vt, yb);

  // out = y · Wp^T  (M=4096 N=2048 K=2048; 256x128 tiles, grid 16x16)
  k_gemmQ<2, float><<<dim3(16, 16), 1024, 0, stream>>>(
      yb, wpf, out, 4096, 2048, 2048, 2048, 2048);
}

// Round 17
// 188.839 us; speedup vs baseline: 1.8248x; 1.0513x over previous
//
#include <hip/hip_runtime.h>
#include <hip/hip_bf16.h>
#include <cstdint>
#include <cstddef>

// ---------------------------------------------------------------------------
// CausalSelfAttention fused block, MI355X/gfx950.  Round 17:
//  - attn: R15 structure (QBLK=64, 1024 blocks, 4 blocks/CU) + R16's V-key
//    fix (write d&7 / read row&7) -- deconfounds R16's two changes; keeps
//    the high-occupancy shape with conflict-free V path.
//  - single k_prep kernel (x/wqkv/wp casts + rope table merged).
//  - GEMMs/epilogue/vtrans unchanged.
// B=2 T=2048 D=2048 NH=16 NKV=4 HD=128 ROPE=64.
// ---------------------------------------------------------------------------

typedef _Float16 f16_t;
typedef f16_t f16x4 __attribute__((ext_vector_type(4)));
typedef f16_t f16x8 __attribute__((ext_vector_type(8)));
typedef float f32x4 __attribute__((ext_vector_type(4)));

#define MFMA16F(a, b, c) __builtin_amdgcn_mfma_f32_16x16x32_f16((a), (b), (c), 0, 0, 0)
#define SBAR()   __builtin_amdgcn_s_barrier()
#define SCHED0() __builtin_amdgcn_sched_barrier(0)
#define LGKM0()  asm volatile("s_waitcnt lgkmcnt(0)" ::: "memory")

__device__ __forceinline__ void gload16(const f16_t* g, f16_t* l) {
  auto lds_ptr = reinterpret_cast<__attribute__((address_space(3))) unsigned int*>(
      reinterpret_cast<uintptr_t>(l));
  auto g_ptr = reinterpret_cast<const __attribute__((address_space(1))) unsigned int*>(
      reinterpret_cast<uintptr_t>(g));
  __builtin_amdgcn_global_load_lds(g_ptr, lds_ptr, 16, 0, 0);
}

__device__ __forceinline__ void cast4(const float* __restrict__ s, f16_t* __restrict__ d) {
  const float4 v = *reinterpret_cast<const float4*>(s);
  f16_t r[4] = {(f16_t)v.x, (f16_t)v.y, (f16_t)v.z, (f16_t)v.w};
  *reinterpret_cast<uint64_t*>(d) = *reinterpret_cast<const uint64_t*>(r);
}

// ---------------------------------------------------------------------------
// merged prep: x->xf, [Wq|Wk|Wv]->wqkvf, Wp->wpf (fp32->fp16), rope tables.
// unit = 4 elements; grid-stride.
// ---------------------------------------------------------------------------
__global__ __launch_bounds__(256) void k_prep(
    const float* __restrict__ x, const float* __restrict__ Wq,
    const float* __restrict__ Wk, const float* __restrict__ Wv,
    const float* __restrict__ Wp, f16_t* __restrict__ xf,
    f16_t* __restrict__ wqkvf, f16_t* __restrict__ wpf,
    float* __restrict__ ctab, float* __restrict__ stab)
{
  const long N4X = 2097152;   // 4096*2048/4
  const long N4W = 1572864;   // 3072*2048/4
  const long N4P = 1048576;   // 2048*2048/4
  const long N4R = 16384;     // 2048*32/4
  long i = (long)blockIdx.x * blockDim.x + threadIdx.x;
  const long step = (long)gridDim.x * blockDim.x;
  for (; i < N4X + N4W + N4P + N4R; i += step) {
    if (i < N4X) {
      cast4(x + i * 4, xf + i * 4);
    } else if (i < N4X + N4W) {
      const long j = (i - N4X) * 4;
      const long row = j >> 11, col = j & 2047;
      const float* src = (row < 2048) ? (Wq + row * 2048)
                       : (row < 2560) ? (Wk + (row - 2048) * 2048)
                                      : (Wv + (row - 2560) * 2048);
      cast4(src + col, wqkvf + j);
    } else if (i < N4X + N4W + N4P) {
      const long j = (i - N4X - N4W) * 4;
      cast4(Wp + j, wpf + j);
    } else {
      const long j = (i - N4X - N4W - N4P) * 4;
#pragma unroll
      for (int k = 0; k < 4; ++k) {
        const long idx = j + k;
        const int t = (int)(idx >> 5), fi = (int)(idx & 31);
        const float freq = exp2f(-(float)fi * 0.2076205059304601f);  // 10000^(-fi/64)
        const float f = (float)t * freq;
        ctab[idx] = cosf(f);
        stab[idx] = sinf(f);
      }
    }
  }
}

// ---------------------------------------------------------------------------
// V transpose: vn [bk][2048 t][128 d] -> vt [bk][128 d][2048 t].
// ---------------------------------------------------------------------------
__global__ __launch_bounds__(256) void k_vtrans(
    const f16_t* __restrict__ vn, f16_t* __restrict__ vt)
{
  __shared__ __align__(16) f16_t lsT[64 * 136];
  const int t0 = blockIdx.x * 64;
  const int bk = blockIdx.y;
  const f16_t* src = vn + ((size_t)bk * 2048 + t0) * 128;
  f16_t* dst = vt + (size_t)bk * 128 * 2048;
  const int tid = threadIdx.x;
#pragma unroll
  for (int it = 0; it < 4; ++it) {
    const int cch = tid + it * 256;
    const int r = cch >> 4, c = cch & 15;
    *reinterpret_cast<f16x8*>(&lsT[r * 136 + c * 8]) =
        *reinterpret_cast<const f16x8*>(src + (size_t)r * 128 + c * 8);
  }
  __syncthreads();
#pragma unroll
  for (int it = 0; it < 4; ++it) {
    const int u = tid + it * 256;
    const int d = u >> 3, c8 = u & 7;
    f16_t vals[8];
#pragma unroll
    for (int j = 0; j < 8; ++j) vals[j] = lsT[(c8 * 8 + j) * 136 + d];
    *reinterpret_cast<f16x8*>(dst + (size_t)d * 2048 + t0 + c8 * 8) =
        *reinterpret_cast<const f16x8*>(vals);
  }
}

// ---------------------------------------------------------------------------
// 256 x (64*NBU) NT GEMM, fp16 in, OutT out (R10/R11 proven).
// 1024 threads = 16 waves (4M x 4N); BK=64; 2-phase counted-vmcnt.
// ---------------------------------------------------------------------------
template <int NBU, typename OutT>
__global__ __launch_bounds__(1024, 1) void k_gemmQ(
    const f16_t* __restrict__ A, const f16_t* __restrict__ Bm,
    OutT* __restrict__ C, int M, int N, int K, int lda, int ldb)
{
  __shared__ __align__(16) f16_t lds[2][(4 + NBU) * 4096];
  const int tid = threadIdx.x;
  const int l = tid & 63, w = tid >> 6;       // w 0..15
  const int lrow = l & 15, lk = l >> 4;
  const int wm = w >> 2, wn = w & 3;          // 4 x 4 wave grid

  const int nwg = gridDim.x * gridDim.y;
  int lin = blockIdx.y * gridDim.x + blockIdx.x;
  lin = (lin & 7) * (nwg >> 3) + (lin >> 3);
  const int m0 = (lin / gridDim.x) * 256, n0 = (lin % gridDim.x) * (64 * NBU);

  const bool stager = (tid < 512);
  const int srow = tid >> 3;
  const int scol = ((tid & 7) ^ (srow & 7)) << 3;
  const f16_t* gP[4 + NBU];
#pragma unroll
  for (int u = 0; u < 4; ++u) gP[u] = A + (size_t)(m0 + u * 64 + srow) * lda + scol;
#pragma unroll
  for (int u = 0; u < NBU; ++u) gP[4 + u] = Bm + (size_t)(n0 + u * 64 + srow) * ldb + scol;

  auto stageAll = [&](int buf, int k0) {
#pragma unroll
    for (int u = 0; u < 4 + NBU; ++u)
      gload16(gP[u] + k0, &lds[buf][u * 4096 + tid * 8]);
  };
  auto rdA = [&](int buf, int mf, int ks) -> f16x8 {
    const int row = wm * 64 + mf * 16 + lrow;             // 0..255
    const int slot = ((ks << 2) | lk) ^ (row & 7);
    return *reinterpret_cast<const f16x8*>(&lds[buf][row * 64 + slot * 8]);
  };
  auto rdB = [&](int buf, int nf, int ks) -> f16x8 {
    const int row = wn * (16 * NBU) + nf * 16 + lrow;     // 0..64*NBU-1
    const int slot = ((ks << 2) | lk) ^ (row & 7);
    return *reinterpret_cast<const f16x8*>(&lds[buf][16384 + row * 64 + slot * 8]);
  };

  f32x4 acc[4][NBU] = {};
  const int nkt = K >> 6;

  if (stager) {
    stageAll(0, 0);
    stageAll(1, nkt > 1 ? 64 : 0);
  }
  if constexpr (NBU == 3) { asm volatile("s_waitcnt vmcnt(7)" ::: "memory"); }
  else                    { asm volatile("s_waitcnt vmcnt(6)" ::: "memory"); }
  SCHED0();
  SBAR(); SCHED0();

  f16x8 aA[4][2], bB[NBU][2];
  for (int kt = 0; kt < nkt; ++kt) {
    const int b = kt & 1;
    const int kn2 = (kt + 2 < nkt ? kt + 2 : nkt - 1) << 6;

    // phase 1: read all frags of tile t, MFMA mf 0..1
#pragma unroll
    for (int mf = 0; mf < 4; ++mf) { aA[mf][0] = rdA(b, mf, 0); aA[mf][1] = rdA(b, mf, 1); }
#pragma unroll
    for (int nf = 0; nf < NBU; ++nf) { bB[nf][0] = rdB(b, nf, 0); bB[nf][1] = rdB(b, nf, 1); }
    __builtin_amdgcn_s_setprio(1);
#pragma unroll
    for (int mf = 0; mf < 2; ++mf)
#pragma unroll
      for (int nf = 0; nf < NBU; ++nf)
#pragma unroll
        for (int ks = 0; ks < 2; ++ks)
          acc[mf][nf] = MFMA16F(aA[mf][ks], bB[nf][ks], acc[mf][nf]);
    __builtin_amdgcn_s_setprio(0);
    LGKM0(); SCHED0();
    SBAR(); SCHED0();

    // phase 2: stage tile t+2 over dead buf b; wait tile t+1; MFMA mf 2..3
    if (stager) stageAll(b, kn2);
    if constexpr (NBU == 3) { asm volatile("s_waitcnt vmcnt(7)" ::: "memory"); }
    else                    { asm volatile("s_waitcnt vmcnt(6)" ::: "memory"); }
    SCHED0();
    __builtin_amdgcn_s_setprio(1);
#pragma unroll
    for (int mf = 2; mf < 4; ++mf)
#pragma unroll
      for (int nf = 0; nf < NBU; ++nf)
#pragma unroll
        for (int ks = 0; ks < 2; ++ks)
          acc[mf][nf] = MFMA16F(aA[mf][ks], bB[nf][ks], acc[mf][nf]);
    __builtin_amdgcn_s_setprio(0);
    SBAR(); SCHED0();
  }

  // C-write
#pragma unroll
  for (int mf = 0; mf < 4; ++mf) {
    const int row = m0 + wm * 64 + mf * 16 + lk * 4;
#pragma unroll
    for (int nf = 0; nf < NBU; ++nf) {
      const int col = n0 + wn * (16 * NBU) + nf * 16 + lrow;
#pragma unroll
      for (int rg = 0; rg < 4; ++rg)
        C[(size_t)(row + rg) * N + col] = (OutT)acc[mf][nf][rg];
    }
  }
  (void)M;
}

// ---------------------------------------------------------------------------
// QKV epilogue (unchanged from R11).
// ---------------------------------------------------------------------------
__global__ __launch_bounds__(256) void k_qkv_epi(
    const f16_t* __restrict__ qkv, const float* __restrict__ ve,
    const float* __restrict__ qgain,
    const float* __restrict__ ctab, const float* __restrict__ stab,
    f16_t* __restrict__ qn, f16_t* __restrict__ kn, f16_t* __restrict__ vn)
{
  const int blk = blockIdx.x;           // b*2048 + t
  const int b = blk >> 11, t = blk & 2047;
  const int w = threadIdx.x >> 6, l = threadIdx.x & 63;
  const int i32 = l & 31;
  const float c = ctab[t * 32 + i32], s = stab[t * 32 + i32];
  const float EPS = 1.1920929e-07f;
  constexpr float SCALE_L2E = 0.088388347648318447f * 1.4426950408889634f;

#pragma unroll
  for (int it = 0; it < 4; ++it) {
    const int h = w + it * 4;
    const f16_t* row = qkv + (size_t)blk * 3072 + h * 128;
    float x0 = (float)row[l], x1 = (float)row[l + 64];
    float ss = x0 * x0 + x1 * x1;
#pragma unroll
    for (int off = 32; off; off >>= 1) ss += __shfl_xor(ss, off);
    const float rn = rsqrtf(ss * (1.0f / 128.0f) + EPS);
    x0 *= rn; x1 *= rn;
    const float p = __shfl_xor(x0, 32);
    float xr = (l < 32) ? (x0 * c - p * s) : (p * s + x0 * c);
    const float g = qgain[h] * SCALE_L2E;
    xr *= g; x1 *= g;
    f16_t* orow = qn + (((size_t)(b * 16 + h)) * 2048 + t) * 128;
    orow[l] = (f16_t)xr;
    orow[l + 64] = (f16_t)x1;
  }
  {
    const f16_t* row = qkv + (size_t)blk * 3072 + 2048 + w * 128;
    float x0 = (float)row[l], x1 = (float)row[l + 64];
    float ss = x0 * x0 + x1 * x1;
#pragma unroll
    for (int off = 32; off; off >>= 1) ss += __shfl_xor(ss, off);
    const float rn = rsqrtf(ss * (1.0f / 128.0f) + EPS);
    x0 *= rn; x1 *= rn;
    const float p = __shfl_xor(x0, 32);
    const float xr = (l < 32) ? (x0 * c - p * s) : (p * s + x0 * c);
    f16_t* orow = kn + (((size_t)(b * 4 + w)) * 2048 + t) * 128;
    orow[l] = (f16_t)xr;
    orow[l + 64] = (f16_t)x1;
  }
  {
    const f16_t* row = qkv + (size_t)blk * 3072 + 2560 + w * 128;
    const float* verow = ve + (size_t)blk * 512 + w * 128;
    f16_t* orow = vn + (((size_t)(b * 4 + w)) * 2048 + t) * 128;
    orow[l] = (f16_t)((float)row[l] + verow[l]);
    orow[l + 64] = (f16_t)((float)row[l + 64] + verow[l + 64]);
  }
}

// ---------------------------------------------------------------------------
// Causal GQA flash attention, fp16, swapped QK^T (S^T = mfma(K,Q)): lane
// holds S[q=lrow][kv=cf*16+lk*4+rg] -> lane-local softmax.  QBLK=64 (4 waves
// x 16 q-rows), KVBLK=64, longest-qt-first, grid 32x32 (4 blocks/CU).
// LDS (XOR-swizzled, 40960B): lsK [64][128] key r&7; lsV^T [128][64] key d&7
// (R16 fix: full 8-group spread); lsP [4][16][64] key lrow&7.  lb(256,3).
// ---------------------------------------------------------------------------
__global__ __launch_bounds__(256, 3) void k_attn(
    const f16_t* __restrict__ qn, const f16_t* __restrict__ kn,
    const f16_t* __restrict__ vt, f16_t* __restrict__ y)
{
  __shared__ __align__(16) f16_t lsK[64 * 128];      // 16384 B
  __shared__ __align__(16) f16_t lsV[128 * 64];      // 16384 B
  __shared__ __align__(16) f16_t lsPb[4][16 * 64];   //  8192 B
  const int qt = 31 - (int)blockIdx.y;  // longest first
  const int bh = blockIdx.x;            // 0..31
  const int b = bh >> 4, h = bh & 15, kvh = h >> 2;
  const int tid = threadIdx.x, w = tid >> 6, l = tid & 63;
  const int lrow = l & 15, lk = l >> 4;
  const int qbase = qt * 64 + w * 16;
  constexpr float NEG = -1e30f;
  f16_t* lsP = lsPb[w];

  // Q fragments (row/col = lane&15, k = lk*8+j)
  const f16_t* qp = qn + ((size_t)(b * 16 + h) * 2048) * 128;
  f16x8 aQ[4];
#pragma unroll
  for (int kf = 0; kf < 4; ++kf)
    aQ[kf] = *reinterpret_cast<const f16x8*>(
        qp + (size_t)(qbase + lrow) * 128 + kf * 32 + lk * 8);

  const f16_t* kp = kn + ((size_t)(b * 4 + kvh) * 2048) * 128;
  const f16_t* vtp = vt + (size_t)(b * 4 + kvh) * 128 * 2048;

  f32x4 o[8] = {};
  float mst = NEG;   // running max for THIS LANE's q-row (q = lrow)
  float lst = 0.f;   // per-lane partial sum for q = lrow (reduced at end)

  f16x8 kreg[4], vreg[4];
  auto loadKV = [&](int t0) {
#pragma unroll
    for (int it = 0; it < 4; ++it) {
      const int cch = tid + it * 256;
      kreg[it] = *reinterpret_cast<const f16x8*>(
          kp + (size_t)(t0 + (cch >> 4)) * 128 + (cch & 15) * 8);
      vreg[it] = *reinterpret_cast<const f16x8*>(
          vtp + (size_t)(cch >> 3) * 2048 + t0 + (cch & 7) * 8);
    }
  };
  loadKV(0);

  const int ntiles = qt + 1;
  for (int tt = 0; tt < ntiles; ++tt) {
    __syncthreads();  // prior tile's K/V LDS reads done before restage
    // stage K [64][128] slot^=(r&7); V^T [128][64] slot8^=(d&7); all b128
#pragma unroll
    for (int it = 0; it < 4; ++it) {
      const int cch = tid + it * 256;
      const int r = cch >> 4, dg = cch & 15;
      *reinterpret_cast<f16x8*>(&lsK[r * 128 + ((dg ^ (r & 7)) << 3)]) = kreg[it];
      const int d = cch >> 3, c8 = cch & 7;
      *reinterpret_cast<f16x8*>(&lsV[d * 64 + ((c8 ^ (d & 7)) << 3)]) = vreg[it];
    }
    if (tt + 1 < ntiles) loadKV((tt + 1) * 64);
    __syncthreads();  // staged data visible

    // S^T = K Q^T: sacc[cf][rg] = S[q=lrow][kv = cf*16 + lk*4 + rg]
    f32x4 sacc[4] = {};
#pragma unroll
    for (int cf = 0; cf < 4; ++cf) {
      const int krow = cf * 16 + lrow;
#pragma unroll
      for (int kf = 0; kf < 4; ++kf) {
        const f16x8 aK = *reinterpret_cast<const f16x8*>(
            &lsK[krow * 128 + ((((kf << 2) | lk) ^ (krow & 7)) << 3)]);
        sacc[cf] = MFMA16F(aK, aQ[kf], sacc[cf]);
      }
    }

    // mask (diagonal tile only): kv_in_tile > q_in_block
    if (tt == qt) {
      const int qin = w * 16 + lrow;
#pragma unroll
      for (int cf = 0; cf < 4; ++cf)
#pragma unroll
        for (int rg = 0; rg < 4; ++rg)
          if (cf * 16 + lk * 4 + rg > qin) sacc[cf][rg] = NEG;
    }

    // lane-local max of this tile's 16 values
    float mx = NEG;
#pragma unroll
    for (int cf = 0; cf < 4; ++cf)
      mx = fmaxf(mx, fmaxf(fmaxf(sacc[cf][0], sacc[cf][1]),
                           fmaxf(sacc[cf][2], sacc[cf][3])));
    if (__any(mx > mst + 8.f)) {
      // row-consistent new max over the 4 lk-lanes holding this q-row
      float rmx = mx;
      rmx = fmaxf(rmx, __shfl_xor(rmx, 16));
      rmx = fmaxf(rmx, __shfl_xor(rmx, 32));
      const float mnew = fmaxf(mst, rmx);
      const float alpha = exp2f(mst - mnew);
      mst = mnew;
      lst *= alpha;
      // o rows are q = lk*4+rg; fetch that row's alpha from lane (lk*4+rg)
#pragma unroll
      for (int rg = 0; rg < 4; ++rg) {
        const float arow = __shfl(alpha, lk * 4 + rg);
#pragma unroll
        for (int df = 0; df < 8; ++df) o[df][rg] *= arow;
      }
    }
    // P = exp2(S - mst), lane-local partial sum
#pragma unroll
    for (int cf = 0; cf < 4; ++cf) {
#pragma unroll
      for (int rg = 0; rg < 4; ++rg) {
        const float p = exp2f(sacc[cf][rg] - mst);
        sacc[cf][rg] = p;
        lst += p;
      }
    }

    // P -> LDS [q=16][kv=64], b64 per cf (kv = cf*16+lk*4 .. +3), XOR slot8
#pragma unroll
    for (int cf = 0; cf < 4; ++cf) {
      f16x4 pk;
#pragma unroll
      for (int rg = 0; rg < 4; ++rg) pk[rg] = (f16_t)sacc[cf][rg];
      const int slot8 = cf * 2 + (lk >> 1);
      *reinterpret_cast<f16x4*>(
          &lsP[lrow * 64 + ((slot8 ^ (lrow & 7)) << 3) + (lk & 1) * 4]) = pk;
    }
    // PV: aP = P[q=lrow][kv=k2*32+lk*8+j]; bV = V[kv][d=df*16+lrow]
#pragma unroll
    for (int k2 = 0; k2 < 2; ++k2) {
      const f16x8 aP = *reinterpret_cast<const f16x8*>(
          &lsP[lrow * 64 + ((((k2 << 2) | lk) ^ (lrow & 7)) << 3)]);
#pragma unroll
      for (int df = 0; df < 8; ++df) {
        const int row = df * 16 + lrow;
        const f16x8 bV = *reinterpret_cast<const f16x8*>(
            &lsV[row * 64 + ((((k2 << 2) | lk) ^ (row & 7)) << 3)]);
        o[df] = MFMA16F(aP, bV, o[df]);
      }
    }
  }

  // reduce lst over the 4 lk-lane copies of each q-row
  lst += __shfl_xor(lst, 16);
  lst += __shfl_xor(lst, 32);

  // normalize + write y: o[df][rg] is q = lk*4+rg, d = df*16+lrow
#pragma unroll
  for (int rg = 0; rg < 4; ++rg) {
    const float lrow_sum = __shfl(lst, lk * 4 + rg);
    const float inv = 1.0f / lrow_sum;
    const int qi = qbase + lk * 4 + rg;
    const size_t rowoff = ((size_t)(b * 2048 + qi)) * 2048 + h * 128;
#pragma unroll
    for (int df = 0; df < 8; ++df)
      y[rowoff + df * 16 + lrow] = (f16_t)(o[df][rg] * inv);
  }
}

// ---------------------------------------------------------------------------
extern "C" void kernel_launch(void* const* d_in, const int* in_sizes, int n_in,
                              void* d_out, int out_size, void* d_ws, size_t ws_size,
                              hipStream_t stream) {
  const float* x  = (const float*)d_in[0];
  const float* ve = (const float*)d_in[1];
  const float* Wq = (const float*)d_in[2];
  const float* Wk = (const float*)d_in[3];
  const float* Wv = (const float*)d_in[4];
  const float* Wp = (const float*)d_in[5];
  const float* qg = (const float*)d_in[6];
  float* out = (float*)d_out;

  char* ws = (char*)d_ws;
  size_t off = 0;
  auto alloc = [&](size_t bytes) -> char* {
    char* p = ws + off;
    off += (bytes + 255) & ~(size_t)255;
    return p;
  };

  f16_t* xf    = (f16_t*)alloc((size_t)4096 * 2048 * 2);   // later qn
  f16_t* wqkvf = (f16_t*)alloc((size_t)3072 * 2048 * 2);   // rows Wq|Wk|Wv
  f16_t* wpf   = (f16_t*)alloc((size_t)2048 * 2048 * 2);
  f16_t* qkvf  = (f16_t*)alloc((size_t)4096 * 3072 * 2);   // GEMM out; later yb
  f16_t* kn    = (f16_t*)alloc((size_t)2 * 4 * 2048 * 128 * 2);
  f16_t* vn    = (f16_t*)alloc((size_t)2 * 4 * 2048 * 128 * 2);
  f16_t* vt    = (f16_t*)alloc((size_t)2 * 4 * 128 * 2048 * 2);
  float* ctab  = (float*)alloc((size_t)2048 * 32 * 4);
  float* stab  = (float*)alloc((size_t)2048 * 32 * 4);
  f16_t* qn    = xf;      // xf dead after QKV GEMM
  f16_t* yb    = qkvf;    // qkvf dead after epilogue
  (void)ws_size; (void)in_sizes; (void)n_in; (void)out_size;

  k_prep<<<2048, 256, 0, stream>>>(x, Wq, Wk, Wv, Wp, xf, wqkvf, wpf, ctab, stab);

  // qkvf = x·[Wq|Wk|Wv]^T  (M=4096 N=3072 K=2048; 256x192 tiles, grid 16x16)
  k_gemmQ<3, f16_t><<<dim3(16, 16), 1024, 0, stream>>>(
      xf, wqkvf, qkvf, 4096, 3072, 2048, 2048, 2048);

  k_qkv_epi<<<4096, 256, 0, stream>>>(qkvf, ve, qg, ctab, stab, qn, kn, vn);

  k_vtrans<<<dim3(32, 8), 256, 0, stream>>>(vn, vt);

  k_attn<<<dim3(32, 32), 256, 0, stream>>>(qn, kn, vt, yb);

  // out = y · Wp^T  (M=4096 N=2048 K=2048; 256x128 tiles, grid 16x16)
  k_gemmQ<2, float><<<dim3(16, 16), 1024, 0, stream>>>(
      yb, wpf, out, 4096, 2048, 2048, 2048, 2048);
}